// Round 1
// baseline (4648.309 us; speedup 1.0000x reference)
//
#include <hip/hip_runtime.h>
#include <math.h>

#define NW 64
#define NS 5
#define NQ 195
#define DIM 1536
#define NTOT 12800
#define NL 320
#define NU 12480
#define ALPHA 0.2f
#define EPOCHS 20
#define EPSC 1e-6f
#define MAXIT 1000
#define SB_NB 49

// ---------------- helpers ----------------
__device__ inline float wave_sum(float x){
#pragma unroll
  for(int o=32;o;o>>=1) x += __shfl_xor(x,o);
  return x;
}
__device__ inline float wave_max(float x){
#pragma unroll
  for(int o=32;o;o>>=1) x = fmaxf(x, __shfl_xor(x,o));
  return x;
}

// one-counter sense-reversing grid barrier (49 co-resident blocks, agent scope)
__device__ inline void grid_barrier(int* cnt, int* gen){
  __syncthreads();
  if(threadIdx.x == 0){
    __threadfence();
    int g = __hip_atomic_load(gen, __ATOMIC_RELAXED, __HIP_MEMORY_SCOPE_AGENT);
    int prev = __hip_atomic_fetch_add(cnt, 1, __ATOMIC_ACQ_REL, __HIP_MEMORY_SCOPE_AGENT);
    if(prev == SB_NB-1){
      __hip_atomic_store(cnt, 0, __ATOMIC_RELAXED, __HIP_MEMORY_SCOPE_AGENT);
      __hip_atomic_store(gen, g+1, __ATOMIC_RELEASE, __HIP_MEMORY_SCOPE_AGENT);
    } else {
      while(__hip_atomic_load(gen, __ATOMIC_ACQUIRE, __HIP_MEMORY_SCOPE_AGENT) == g)
        __builtin_amdgcn_s_sleep(1);
    }
    __threadfence();
  }
  __syncthreads();
}

// ---------------- K1: sqrt power transform + row l2norm + segment column sums ----------------
// 200 blocks x 256 threads, wave-per-row (4 waves, 16 reps -> 64 rows/block)
__global__ __launch_bounds__(256) void k_prep(const float* __restrict__ X, float* __restrict__ Z,
                                              float* __restrict__ csum_l, float* __restrict__ csum_u){
  int b = blockIdx.x;
  int wv = threadIdx.x >> 6, lane = threadIdx.x & 63;
  float racc[24];
#pragma unroll
  for(int q=0;q<24;q++) racc[q]=0.f;
  for(int rep=0; rep<16; rep++){
    int row = b*64 + wv + 4*rep;
    const float4* xp = (const float4*)(X + (size_t)row*DIM);
    float4 v[6]; float ss = 0.f;
#pragma unroll
    for(int q=0;q<6;q++){
      float4 t = xp[lane + 64*q];
      t.x = sqrtf(t.x+1e-6f); t.y = sqrtf(t.y+1e-6f); t.z = sqrtf(t.z+1e-6f); t.w = sqrtf(t.w+1e-6f);
      v[q]=t; ss += t.x*t.x+t.y*t.y+t.z*t.z+t.w*t.w;
    }
    ss = wave_sum(ss);
    float inv = 1.f / fmaxf(sqrtf(ss), 1e-12f);
    float4* zp = (float4*)(Z + (size_t)row*DIM);
#pragma unroll
    for(int q=0;q<6;q++){
      float4 t = v[q]; t.x*=inv; t.y*=inv; t.z*=inv; t.w*=inv;
      zp[lane + 64*q] = t;
      racc[4*q+0]+=t.x; racc[4*q+1]+=t.y; racc[4*q+2]+=t.z; racc[4*q+3]+=t.w;
    }
  }
  float* dst = (b < 5) ? csum_l : csum_u;   // blocks 0..4 are exactly rows 0..319
#pragma unroll
  for(int q=0;q<6;q++){
    int c = 4*(lane + 64*q);
    atomicAdd(&dst[c+0], racc[4*q+0]); atomicAdd(&dst[c+1], racc[4*q+1]);
    atomicAdd(&dst[c+2], racc[4*q+2]); atomicAdd(&dst[c+3], racc[4*q+3]);
  }
}

// ---------------- K2: column sums -> means ----------------
__global__ void k_finalize_means(float* csum_l, float* csum_u){
  int idx = blockIdx.x*256 + threadIdx.x;
  if(idx < DIM) csum_l[idx] *= (1.0f/NL);
  else if(idx < 2*DIM) csum_u[idx-DIM] *= (1.0f/NU);
}

// ---------------- K3: center per segment + row l2norm (in place on Z) ----------------
__global__ __launch_bounds__(256) void k_center(float* __restrict__ Z,
                                                const float* __restrict__ cm_l, const float* __restrict__ cm_u){
  int b = blockIdx.x;
  int wv = threadIdx.x >> 6, lane = threadIdx.x & 63;
  for(int rep=0; rep<16; rep++){
    int row = b*64 + wv + 4*rep;
    const float4* cp = (const float4*)((row < NL) ? cm_l : cm_u);
    float4* zp = (float4*)(Z + (size_t)row*DIM);
    float4 v[6]; float ss = 0.f;
#pragma unroll
    for(int q=0;q<6;q++){
      float4 t = zp[lane + 64*q];
      float4 m = cp[lane + 64*q];
      t.x-=m.x; t.y-=m.y; t.z-=m.z; t.w-=m.w;
      v[q]=t; ss += t.x*t.x+t.y*t.y+t.z*t.z+t.w*t.w;
    }
    ss = wave_sum(ss);
    float inv = 1.f / fmaxf(sqrtf(ss), 1e-12f);
#pragma unroll
    for(int q=0;q<6;q++){
      float4 t = v[q]; t.x*=inv; t.y*=inv; t.z*=inv; t.w*=inv;
      zp[lane + 64*q] = t;
    }
  }
}

// ---------------- K4: init mus from labeled shots ----------------
__global__ void k_mus_init(const float* __restrict__ Z, float* __restrict__ mus){
  int w = blockIdx.x;
#pragma unroll
  for(int q=0;q<6;q++){
    int c = threadIdx.x + 256*q;
    float s = 0.f;
#pragma unroll
    for(int sh=0; sh<NS; sh++) s += Z[(size_t)(sh*NW + w)*DIM + c];
    mus[(size_t)w*DIM + c] = s * 0.2f;
  }
}

// ---------------- K4b: labeled mask rows = exp(onehot) in {1, e} ----------------
__global__ void k_labeled_mask(const int* __restrict__ labels, float* __restrict__ mask){
  int idx = blockIdx.x*256 + threadIdx.x;   // < 320*64
  if(idx < NL*NW){
    int i = idx >> 6, w = idx & 63;
    mask[idx] = (labels[i]==w) ? expf(1.0f) : 1.0f;
  }
}

// ---------------- K5: per-epoch prep: munorm, zero emus/masksum/matchcount ----------------
__global__ void k_epoch_prep(const float* __restrict__ mus, float* munorm, float* masksum,
                             float* __restrict__ emus, float* matchcount){
  int w = blockIdx.x;
  float ss = 0.f;
#pragma unroll
  for(int q=0;q<6;q++){
    int c = threadIdx.x + 256*q;
    float v = mus[(size_t)w*DIM + c];
    ss += v*v;
    emus[(size_t)w*DIM + c] = 0.f;
  }
  __shared__ float red[4];
  float wsu = wave_sum(ss);
  if((threadIdx.x&63)==0) red[threadIdx.x>>6]=wsu;
  __syncthreads();
  if(threadIdx.x==0){
    munorm[w] = red[0]+red[1]+red[2]+red[3];
    masksum[w] = 0.f;
    if(w==0) *matchcount = 0.f;
  }
}

// ---------------- K6: dist GEMM -> Kmat = exp(-10*dist) for unlabeled rows ----------------
// grid 195 blocks: 64 rows x 64 cols per block, register-blocked 4x4
__global__ __launch_bounds__(256) void k_dist(const float* __restrict__ Z, const float* __restrict__ mus,
                                              const float* __restrict__ munorm, float* __restrict__ Kmat){
  __shared__ __align__(16) float ZT[64][68];
  __shared__ __align__(16) float MT[64][68];
  int b = blockIdx.x;
  int rbase = NL + b*64;
  int t = threadIdx.x, tr = t & 15, tc = t >> 4;
  float acc[4][4] = {{0}};
  for(int kc=0;kc<24;kc++){
    int kb = kc*64;
#pragma unroll
    for(int m=0;m<4;m++){
      int e4 = t + 256*m;
      int r = e4 >> 4, kq = e4 & 15;
      float4 zv = *(const float4*)(Z + (size_t)(rbase + r)*DIM + kb + 4*kq);
      ZT[4*kq+0][r]=zv.x; ZT[4*kq+1][r]=zv.y; ZT[4*kq+2][r]=zv.z; ZT[4*kq+3][r]=zv.w;
      float4 mv = *(const float4*)(mus + (size_t)r*DIM + kb + 4*kq);   // r doubles as w
      MT[4*kq+0][r]=mv.x; MT[4*kq+1][r]=mv.y; MT[4*kq+2][r]=mv.z; MT[4*kq+3][r]=mv.w;
    }
    __syncthreads();
#pragma unroll
    for(int k=0;k<64;k++){
      float4 za = *(const float4*)&ZT[k][4*tr];
      float4 mb = *(const float4*)&MT[k][4*tc];
      acc[0][0]+=za.x*mb.x; acc[0][1]+=za.x*mb.y; acc[0][2]+=za.x*mb.z; acc[0][3]+=za.x*mb.w;
      acc[1][0]+=za.y*mb.x; acc[1][1]+=za.y*mb.y; acc[1][2]+=za.y*mb.z; acc[1][3]+=za.y*mb.w;
      acc[2][0]+=za.z*mb.x; acc[2][1]+=za.z*mb.y; acc[2][2]+=za.z*mb.z; acc[2][3]+=za.z*mb.w;
      acc[3][0]+=za.w*mb.x; acc[3][1]+=za.w*mb.y; acc[3][2]+=za.w*mb.z; acc[3][3]+=za.w*mb.w;
    }
    __syncthreads();
  }
#pragma unroll
  for(int rr=0;rr<4;rr++)
#pragma unroll
    for(int cc=0;cc<4;cc++){
      int iu = b*64 + 4*tr + rr;       // unlabeled row index
      int w = 4*tc + cc;
      float d2 = 1.0f + munorm[w] - 2.0f*acc[rr][cc];
      Kmat[(size_t)iu*NW + w] = expf(-10.0f * sqrtf(fmaxf(d2, 0.0f)));
    }
}

// ---------------- K7: persistent Sinkhorn (device-side while loop) ----------------
// 49 blocks x 256 threads, one row per thread, K row in registers.
__global__ __launch_bounds__(256,1) void k_sinkhorn(const float* __restrict__ Kmat, float* __restrict__ plan,
                                                    float* __restrict__ partials, int* __restrict__ bar){
  __shared__ __align__(16) float vsh[64];
  __shared__ float tmat[256][33];
  __shared__ float tq[8][64];
  __shared__ float tcol[64];
  __shared__ float mred[4];
  __shared__ float ctrl[1];
  int t = threadIdx.x, b = blockIdx.x;
  int iu = b*256 + t;
  bool active = iu < NU;
  float kr[64];
  if(active){
    const float4* kp = (const float4*)(Kmat + (size_t)iu*NW);
#pragma unroll
    for(int q=0;q<16;q++){
      float4 x = kp[q];
      kr[4*q]=x.x; kr[4*q+1]=x.y; kr[4*q+2]=x.z; kr[4*q+3]=x.w;
    }
  } else {
#pragma unroll
    for(int j=0;j<64;j++) kr[j]=0.f;
  }
  if(t < 64) vsh[t] = 1.0f;
  float u = 1.0f, r_old = 0.0f;
  __syncthreads();
  int n = 0;
  while(true){
    // phase A: s_i = K_i . v  (fp64 accumulate for residual stability)
    double s = 0.0;
#pragma unroll
    for(int q=0;q<16;q++){
      float4 vv = *(const float4*)&vsh[4*q];
      s += (double)kr[4*q]*vv.x + (double)kr[4*q+1]*vv.y + (double)kr[4*q+2]*vv.z + (double)kr[4*q+3]*vv.w;
    }
    float sf = (float)s;
    float r = u * sf;
    float diff = fabsf(r - r_old);
    float u_new = (active && sf > 0.f) ? 1.0f/sf : 0.0f;
    float wmx = wave_max(diff);
    if((t&63)==0) mred[t>>6] = wmx;
    // column sums of kr[j]*u_new, two 32-wide halves through LDS transpose
#pragma unroll
    for(int h=0;h<2;h++){
#pragma unroll
      for(int jj=0;jj<32;jj++) tmat[t][jj] = kr[32*h+jj]*u_new;
      __syncthreads();
      {
        int j = t & 31, q = t >> 5;
        float ps = 0.f;
#pragma unroll
        for(int rr=0;rr<32;rr++) ps += tmat[q*32+rr][j];
        tq[q][j] = ps;
      }
      __syncthreads();
      if(t < 32) tcol[32*h + t] = tq[0][t]+tq[1][t]+tq[2][t]+tq[3][t]+tq[4][t]+tq[5][t]+tq[6][t]+tq[7][t];
      __syncthreads();
    }
    int buf = n & 1;
    float* P = partials + buf*(SB_NB*66) + b*66;
    if(t < 64){
      __hip_atomic_store(&P[t], tcol[t], __ATOMIC_RELAXED, __HIP_MEMORY_SCOPE_AGENT);
    } else if(t == 64){
      float bm = fmaxf(fmaxf(mred[0],mred[1]), fmaxf(mred[2],mred[3]));
      __hip_atomic_store(&P[64], bm, __ATOMIC_RELAXED, __HIP_MEMORY_SCOPE_AGENT);
    }
    grid_barrier(bar, bar+1);
    // every block redundantly reduces all partials
    {
      int j = t & 63, q4 = t >> 6;
      float ps = 0.f, pm = 0.f;
      const float* PB = partials + buf*(SB_NB*66);
      for(int bb=q4; bb<SB_NB; bb+=4){
        ps += __hip_atomic_load(&PB[bb*66 + j], __ATOMIC_RELAXED, __HIP_MEMORY_SCOPE_AGENT);
        if(j==0) pm = fmaxf(pm, __hip_atomic_load(&PB[bb*66 + 64], __ATOMIC_RELAXED, __HIP_MEMORY_SCOPE_AGENT));
      }
      tq[q4][j] = ps;
      if(j==0) mred[q4] = pm;
    }
    __syncthreads();
    if(t==0) ctrl[0] = fmaxf(fmaxf(mred[0],mred[1]), fmaxf(mred[2],mred[3]));
    __syncthreads();
    float M = ctrl[0];
    if(M <= EPSC || n >= MAXIT) break;   // exit with pre-update u, v (matches jax.lax.while_loop semantics)
    u = u_new; r_old = r; n++;
    if(t < 64) vsh[t] = (float)NQ / (tq[0][t]+tq[1][t]+tq[2][t]+tq[3][t]);
    __syncthreads();
  }
  if(active){
    float* pp = plan + (size_t)iu*NW;
#pragma unroll
    for(int q=0;q<16;q++){
      float4 o;
      o.x = kr[4*q+0]*u*vsh[4*q+0];
      o.y = kr[4*q+1]*u*vsh[4*q+1];
      o.z = kr[4*q+2]*u*vsh[4*q+2];
      o.w = kr[4*q+3]*u*vsh[4*q+3];
      *(float4*)(pp + 4*q) = o;
    }
  }
}

// ---------------- K8: emus accumulation: emus[w,c] += sum_i mask[i,w]*Z[i,c] ----------------
// grid (24 c-tiles, 10 i-segments), 64x64 tile, 4x4 register blocking, atomicAdd outputs
__global__ __launch_bounds__(256) void k_emus(const float* __restrict__ mask, const float* __restrict__ Z,
                                              float* __restrict__ emus){
  __shared__ __align__(16) float Msk[64][68];
  __shared__ __align__(16) float Zt[64][68];
  int ct = blockIdx.x, is = blockIdx.y;
  int cb = ct*64;
  int t = threadIdx.x, tr = t & 15, tc = t >> 4;
  float acc[4][4] = {{0}};
  for(int ic=0; ic<20; ic++){
    int ibase = is*1280 + ic*64;
#pragma unroll
    for(int m=0;m<4;m++){
      int e4 = t + 256*m;
      int ii = e4 >> 4, xq = e4 & 15;
      *(float4*)&Msk[ii][4*xq] = *(const float4*)(mask + (size_t)(ibase+ii)*NW + 4*xq);
      *(float4*)&Zt[ii][4*xq]  = *(const float4*)(Z + (size_t)(ibase+ii)*DIM + cb + 4*xq);
    }
    __syncthreads();
#pragma unroll
    for(int ii=0;ii<64;ii++){
      float4 aw = *(const float4*)&Msk[ii][4*tr];   // w direction
      float4 zc = *(const float4*)&Zt[ii][4*tc];    // c direction
      acc[0][0]+=aw.x*zc.x; acc[0][1]+=aw.x*zc.y; acc[0][2]+=aw.x*zc.z; acc[0][3]+=aw.x*zc.w;
      acc[1][0]+=aw.y*zc.x; acc[1][1]+=aw.y*zc.y; acc[1][2]+=aw.y*zc.z; acc[1][3]+=aw.y*zc.w;
      acc[2][0]+=aw.z*zc.x; acc[2][1]+=aw.z*zc.y; acc[2][2]+=aw.z*zc.z; acc[2][3]+=aw.z*zc.w;
      acc[3][0]+=aw.w*zc.x; acc[3][1]+=aw.w*zc.y; acc[3][2]+=aw.w*zc.z; acc[3][3]+=aw.w*zc.w;
    }
    __syncthreads();
  }
#pragma unroll
  for(int rr=0;rr<4;rr++)
#pragma unroll
    for(int cc=0;cc<4;cc++)
      atomicAdd(&emus[(size_t)(4*tr+rr)*DIM + cb + 4*tc + cc], acc[rr][cc]);
}

// ---------------- K8b: masksum[w] = sum_i mask[i,w] ----------------
__global__ void k_masksum(const float* __restrict__ mask, float* __restrict__ masksum){
  int t = threadIdx.x;
  int w = t & 63, q = t >> 6;
  float s = 0.f;
  for(int rep=0; rep<50; rep++){
    int i = blockIdx.x*200 + rep*4 + q;
    s += mask[(size_t)i*NW + w];
  }
  __shared__ float red[4][64];
  red[q][w] = s;
  __syncthreads();
  if(t < 64) atomicAdd(&masksum[t], red[0][t]+red[1][t]+red[2][t]+red[3][t]);
}

// ---------------- K9: mus update ----------------
__global__ void k_mus_update(float* __restrict__ mus, const float* __restrict__ emus,
                             const float* __restrict__ masksum){
  int idx = blockIdx.x*256 + threadIdx.x;   // < 64*1536
  int w = idx / DIM;
  float e = emus[idx] / masksum[w];
  mus[idx] += ALPHA * (e - mus[idx]);
}

// ---------------- K10: write P (onehot rows + log plan rows) ----------------
__global__ void k_out(const float* __restrict__ mask, const int* __restrict__ labels, float* __restrict__ out){
  int idx = blockIdx.x*256 + threadIdx.x;   // < 819200
  if(idx < NL*NW){
    int i = idx >> 6, w = idx & 63;
    out[idx] = (labels[i]==w) ? 1.0f : 0.0f;
  } else {
    out[idx] = logf(mask[idx]);              // mask rows >= 320 hold the final plan
  }
}

// ---------------- K11: accuracy partial ----------------
__global__ void k_acc(const float* __restrict__ mask, const int* __restrict__ labels, float* matchcount){
  int iu = blockIdx.x*256 + threadIdx.x;
  float m = 0.f;
  if(iu < NU){
    const float* row = mask + (size_t)(NL+iu)*NW;
    float best = row[0]; int bj = 0;
#pragma unroll
    for(int j=1;j<64;j++){ float v = row[j]; if(v > best){ best = v; bj = j; } }
    m = (labels[NL+iu] == bj) ? 1.f : 0.f;
  }
  float ws = wave_sum(m);
  __shared__ float red[4];
  if((threadIdx.x&63)==0) red[threadIdx.x>>6]=ws;
  __syncthreads();
  if(threadIdx.x==0) atomicAdd(matchcount, red[0]+red[1]+red[2]+red[3]);
}

// ---------------- K12: finalize acc & pm ----------------
__global__ void k_fin(const float* matchcount, float* __restrict__ out){
  out[(size_t)NTOT*NW]     = (*matchcount) * (1.0f/(float)NU);
  out[(size_t)NTOT*NW + 1] = 0.0f;   // pm = 1.96*std(scalar) = 0
}

// ---------------- launch ----------------
extern "C" void kernel_launch(void* const* d_in, const int* in_sizes, int n_in,
                              void* d_out, int out_size, void* d_ws, size_t ws_size,
                              hipStream_t stream){
  const float* X = (const float*)d_in[0];
  const int* labels = (const int*)d_in[1];
  float* out = (float*)d_out;
  float* ws = (float*)d_ws;

  // ws layout (float offsets); total 21,485,000 floats ~ 85.9 MB
  int*   bar        = (int*)ws;           // [2]
  float* matchcount = ws + 2;             // [1]
  float* munorm     = ws + 4;             // [64]
  float* masksum    = ws + 68;            // [64]
  float* csum_l     = ws + 132;           // [1536]
  float* csum_u     = ws + 1668;          // [1536]
  float* mus        = ws + 3204;          // [64*1536]
  float* emus       = ws + 101508;        // [64*1536]
  float* partials   = ws + 199812;        // [2*49*66]
  float* mask       = ws + 206280;        // [12800*64]
  float* Kmat       = ws + 1025480;       // [12480*64]
  float* Z          = ws + 1824200;       // [12800*1536]
  if(ws_size < (size_t)21485000*4) return;

  // zero barrier, matchcount, munorm, masksum, colsums (ws is poisoned 0xAA)
  hipMemsetAsync(ws, 0, 3204*sizeof(float), stream);

  k_prep<<<200,256,0,stream>>>(X, Z, csum_l, csum_u);
  k_finalize_means<<<12,256,0,stream>>>(csum_l, csum_u);
  k_center<<<200,256,0,stream>>>(Z, csum_l, csum_u);
  k_mus_init<<<64,256,0,stream>>>(Z, mus);
  k_labeled_mask<<<80,256,0,stream>>>(labels, mask);

  for(int e=0; e<=EPOCHS; e++){
    k_epoch_prep<<<64,256,0,stream>>>(mus, munorm, masksum, emus, matchcount);
    k_dist<<<195,256,0,stream>>>(Z, mus, munorm, Kmat);
    k_sinkhorn<<<SB_NB,256,0,stream>>>(Kmat, mask + NL*NW, partials, bar);
    if(e < EPOCHS){
      k_emus<<<dim3(24,10),256,0,stream>>>(mask, Z, emus);
      k_masksum<<<64,256,0,stream>>>(mask, masksum);
      k_mus_update<<<384,256,0,stream>>>(mus, emus, masksum);
    }
  }
  k_out<<<3200,256,0,stream>>>(mask, labels, out);
  k_acc<<<49,256,0,stream>>>(mask, labels, matchcount);
  k_fin<<<1,1,0,stream>>>(matchcount, out);
}

// Round 2
// 3392.411 us; speedup vs baseline: 1.3702x; 1.3702x over previous
//
#include <hip/hip_runtime.h>
#include <math.h>

#define NW 64
#define NS 5
#define NQ 195
#define DIM 1536
#define NTOT 12800
#define NL 320
#define NU 12480
#define ALPHA 0.2f
#define EPOCHS 20
#define EPSC 1e-6f
#define MAXIT 1000
#define SB_NB 49

typedef float f32x4 __attribute__((ext_vector_type(4)));
typedef short short8 __attribute__((ext_vector_type(8)));

// ---------------- helpers ----------------
__device__ inline float wave_sum(float x){
#pragma unroll
  for(int o=32;o;o>>=1) x += __shfl_xor(x,o);
  return x;
}
__device__ inline float wave_max(float x){
#pragma unroll
  for(int o=32;o;o>>=1) x = fmaxf(x, __shfl_xor(x,o));
  return x;
}
__device__ inline float bf2f(ushort h){
  union{uint u; float f;} c; c.u = ((uint)h)<<16; return c.f;
}
__device__ inline ushort f2bf(float x){
  union{float f; uint u;} c; c.f = x;
  uint r = c.u + 0x7FFFu + ((c.u>>16)&1u);
  return (ushort)(r>>16);
}
__device__ inline void split4(float4 v, ushort4& h, ushort4& l){
  h.x=f2bf(v.x); l.x=f2bf(v.x-bf2f(h.x));
  h.y=f2bf(v.y); l.y=f2bf(v.y-bf2f(h.y));
  h.z=f2bf(v.z); l.z=f2bf(v.z-bf2f(h.z));
  h.w=f2bf(v.w); l.w=f2bf(v.w-bf2f(h.w));
}

// ---------------- K1: sqrt power transform + row l2norm -> Z hi/lo bf16 ----------------
// 3200 blocks x 256 threads, wave-per-row
__global__ __launch_bounds__(256) void k_prep(const float* __restrict__ X, ushort* __restrict__ Zhi,
                                              ushort* __restrict__ Zlo){
  int row = blockIdx.x*4 + (threadIdx.x>>6);
  int lane = threadIdx.x & 63;
  const float4* xp = (const float4*)(X + (size_t)row*DIM);
  float4 v[6]; float ss = 0.f;
#pragma unroll
  for(int q=0;q<6;q++){
    float4 t = xp[lane + 64*q];
    t.x = sqrtf(t.x+1e-6f); t.y = sqrtf(t.y+1e-6f); t.z = sqrtf(t.z+1e-6f); t.w = sqrtf(t.w+1e-6f);
    v[q]=t; ss += t.x*t.x+t.y*t.y+t.z*t.z+t.w*t.w;
  }
  ss = wave_sum(ss);
  float inv = 1.f / fmaxf(sqrtf(ss), 1e-12f);
#pragma unroll
  for(int q=0;q<6;q++){
    float4 t = v[q]; t.x*=inv; t.y*=inv; t.z*=inv; t.w*=inv;
    ushort4 h,l; split4(t,h,l);
    size_t off = (size_t)row*DIM + 4*lane + 256*q;
    *(ushort4*)&Zhi[off] = h;
    *(ushort4*)&Zlo[off] = l;
  }
}

// ---------------- K2a: segment column sums (streaming, few atomics) ----------------
// grid (3, 100): 512 cols x 128 rows per block
__global__ __launch_bounds__(256) void k_colsum(const ushort* __restrict__ Zhi, const ushort* __restrict__ Zlo,
                                                float* __restrict__ csum_l, float* __restrict__ csum_u){
  int c0 = blockIdx.x*512 + 2*threadIdx.x;
  int r0 = blockIdx.y*128;
  float al0=0.f, al1=0.f, au0=0.f, au1=0.f;
  for(int r=r0; r<r0+128; r++){
    ushort2 h = *(const ushort2*)&Zhi[(size_t)r*DIM + c0];
    ushort2 l = *(const ushort2*)&Zlo[(size_t)r*DIM + c0];
    float x0 = bf2f(h.x)+bf2f(l.x), x1 = bf2f(h.y)+bf2f(l.y);
    if(r < NL){ al0+=x0; al1+=x1; } else { au0+=x0; au1+=x1; }
  }
  if(r0 < NL){ atomicAdd(&csum_l[c0], al0); atomicAdd(&csum_l[c0+1], al1); }
  if(r0+128 > NL){ atomicAdd(&csum_u[c0], au0); atomicAdd(&csum_u[c0+1], au1); }
}

// ---------------- K2b: column sums -> means ----------------
__global__ void k_finalize_means(float* csum_l, float* csum_u){
  int idx = blockIdx.x*256 + threadIdx.x;
  if(idx < DIM) csum_l[idx] *= (1.0f/NL);
  else if(idx < 2*DIM) csum_u[idx-DIM] *= (1.0f/NU);
}

// ---------------- K3: center per segment + row l2norm (in place, hi/lo) ----------------
__global__ __launch_bounds__(256) void k_center(ushort* __restrict__ Zhi, ushort* __restrict__ Zlo,
                                                const float* __restrict__ cm_l, const float* __restrict__ cm_u){
  int row = blockIdx.x*4 + (threadIdx.x>>6);
  int lane = threadIdx.x & 63;
  const float4* cp = (const float4*)((row < NL) ? cm_l : cm_u);
  float4 v[6]; float ss = 0.f;
#pragma unroll
  for(int q=0;q<6;q++){
    size_t off = (size_t)row*DIM + 4*lane + 256*q;
    ushort4 h = *(const ushort4*)&Zhi[off];
    ushort4 l = *(const ushort4*)&Zlo[off];
    float4 m = cp[lane + 64*q];
    float4 t;
    t.x = bf2f(h.x)+bf2f(l.x) - m.x;
    t.y = bf2f(h.y)+bf2f(l.y) - m.y;
    t.z = bf2f(h.z)+bf2f(l.z) - m.z;
    t.w = bf2f(h.w)+bf2f(l.w) - m.w;
    v[q]=t; ss += t.x*t.x+t.y*t.y+t.z*t.z+t.w*t.w;
  }
  ss = wave_sum(ss);
  float inv = 1.f / fmaxf(sqrtf(ss), 1e-12f);
#pragma unroll
  for(int q=0;q<6;q++){
    float4 t = v[q]; t.x*=inv; t.y*=inv; t.z*=inv; t.w*=inv;
    ushort4 h,l; split4(t,h,l);
    size_t off = (size_t)row*DIM + 4*lane + 256*q;
    *(ushort4*)&Zhi[off] = h;
    *(ushort4*)&Zlo[off] = l;
  }
}

// ---------------- K4: init mus from labeled shots ----------------
__global__ void k_mus_init(const ushort* __restrict__ Zhi, const ushort* __restrict__ Zlo,
                           float* __restrict__ mus){
  int w = blockIdx.x;
#pragma unroll
  for(int q=0;q<6;q++){
    int c = threadIdx.x + 256*q;
    float s = 0.f;
#pragma unroll
    for(int sh=0; sh<NS; sh++){
      size_t idx = (size_t)(sh*NW + w)*DIM + c;
      s += bf2f(Zhi[idx]) + bf2f(Zlo[idx]);
    }
    mus[(size_t)w*DIM + c] = s * 0.2f;
  }
}

// ---------------- K4b: labeled mask rows = exp(onehot) in {1, e}; vprev = 1 ----------------
__global__ void k_labeled_mask(const int* __restrict__ labels, float* __restrict__ mask,
                               float* __restrict__ vprev){
  int idx = blockIdx.x*256 + threadIdx.x;   // < 320*64
  if(idx < NL*NW){
    int i = idx >> 6, w = idx & 63;
    mask[idx] = (labels[i]==w) ? expf(1.0f) : 1.0f;
  }
  if(blockIdx.x==0 && threadIdx.x<64) vprev[threadIdx.x] = 1.0f;
}

// ---------------- K5: per-epoch prep: munorm, zero masksum/matchcount, reset stamps ----------------
__global__ void k_epoch_prep(const float* __restrict__ mus, float* munorm, float* masksum,
                             float* matchcount, int* stamps){
  int w = blockIdx.x;
  float ss = 0.f;
#pragma unroll
  for(int q=0;q<6;q++){
    int c = threadIdx.x + 256*q;
    float v = mus[(size_t)w*DIM + c];
    ss += v*v;
  }
  __shared__ float red[4];
  float wsu = wave_sum(ss);
  if((threadIdx.x&63)==0) red[threadIdx.x>>6]=wsu;
  __syncthreads();
  if(threadIdx.x==0){
    munorm[w] = red[0]+red[1]+red[2]+red[3];
    masksum[w] = 0.f;
    if(w==0) *matchcount = 0.f;
    if(w < SB_NB) stamps[w] = 0;
  }
}

// ---------------- K6: dist via MFMA (bf16 hi/lo 3-pass) -> Kmat = exp(-10*dist), bf16 hi/lo ----------------
// C[way][sample] = mus . Z^T ; 195 blocks x 256 threads; wave = 16 samples x 64 ways
__global__ __launch_bounds__(256) void k_dist(const float* __restrict__ mus, const ushort* __restrict__ Zhi,
                                              const ushort* __restrict__ Zlo, const float* __restrict__ munorm,
                                              ushort* __restrict__ Khi, ushort* __restrict__ Klo){
  __shared__ ushort Ahi[2][64][40];   // pitch 40 ushorts = 80B (16B-aligned, odd bank-quad stride)
  __shared__ ushort Alo[2][64][40];
  __shared__ float mn[64];
  int t = threadIdx.x;
  int wv = t>>6, lane = t&63;
  int l15 = lane&15, quad = lane>>4;
  int b = blockIdx.x;
  if(t < 64) mn[t] = munorm[t];
  // staging role: thread t loads 8 fp32 of mus row (t>>2), chunk (t&3)
  int sway = t>>2, sj = t&3;
  const float* msrc = mus + (size_t)sway*DIM + sj*8;
  {
    float4 m0 = *(const float4*)(msrc);
    float4 m1 = *(const float4*)(msrc+4);
    float mv[8] = {m0.x,m0.y,m0.z,m0.w,m1.x,m1.y,m1.z,m1.w};
    short8 sh, sl;
#pragma unroll
    for(int i=0;i<8;i++){
      ushort h = f2bf(mv[i]);
      sh[i] = (short)h; sl[i] = (short)f2bf(mv[i]-bf2f(h));
    }
    *(short8*)&Ahi[0][sway][sj*8] = sh;
    *(short8*)&Alo[0][sway][sj*8] = sl;
  }
  int ig = NL + b*64 + wv*16 + l15;          // global Z row (sample)
  const ushort* bph = Zhi + (size_t)ig*DIM + quad*8;
  const ushort* bpl = Zlo + (size_t)ig*DIM + quad*8;
  short8 bh = *(const short8*)bph;
  short8 bl = *(const short8*)bpl;
  f32x4 acc[4];
#pragma unroll
  for(int q=0;q<4;q++) acc[q] = (f32x4){0.f,0.f,0.f,0.f};
  __syncthreads();
  for(int kt=0; kt<48; kt++){
    int buf = kt&1;
    short8 bh_n = bh, bl_n = bl;
    if(kt < 47){
      bh_n = *(const short8*)(bph + (kt+1)*32);
      bl_n = *(const short8*)(bpl + (kt+1)*32);
      const float* ms = msrc + (kt+1)*32;
      float4 m0 = *(const float4*)(ms);
      float4 m1 = *(const float4*)(ms+4);
      float mv[8] = {m0.x,m0.y,m0.z,m0.w,m1.x,m1.y,m1.z,m1.w};
      short8 sh, sl;
#pragma unroll
      for(int i=0;i<8;i++){
        ushort h = f2bf(mv[i]);
        sh[i] = (short)h; sl[i] = (short)f2bf(mv[i]-bf2f(h));
      }
      *(short8*)&Ahi[buf^1][sway][sj*8] = sh;
      *(short8*)&Alo[buf^1][sway][sj*8] = sl;
    }
#pragma unroll
    for(int q=0;q<4;q++){
      short8 ah = *(const short8*)&Ahi[buf][16*q + l15][quad*8];
      short8 al = *(const short8*)&Alo[buf][16*q + l15][quad*8];
      acc[q] = __builtin_amdgcn_mfma_f32_16x16x32_bf16(ah, bh, acc[q], 0,0,0);
      acc[q] = __builtin_amdgcn_mfma_f32_16x16x32_bf16(al, bh, acc[q], 0,0,0);
      acc[q] = __builtin_amdgcn_mfma_f32_16x16x32_bf16(ah, bl, acc[q], 0,0,0);
    }
    __syncthreads();
    bh = bh_n; bl = bl_n;
  }
  int samp = b*64 + wv*16 + l15;             // Kmat row (unlabeled index)
#pragma unroll
  for(int q=0;q<4;q++){
    float vals[4];
#pragma unroll
    for(int rg=0;rg<4;rg++){
      int w = 16*q + quad*4 + rg;
      float d2 = 1.0f + mn[w] - 2.0f*acc[q][rg];
      vals[rg] = expf(-10.0f * sqrtf(fmaxf(d2, 0.0f)));
    }
    ushort4 oh, ol;
    oh.x=f2bf(vals[0]); ol.x=f2bf(vals[0]-bf2f(oh.x));
    oh.y=f2bf(vals[1]); ol.y=f2bf(vals[1]-bf2f(oh.y));
    oh.z=f2bf(vals[2]); ol.z=f2bf(vals[2]-bf2f(oh.z));
    oh.w=f2bf(vals[3]); ol.w=f2bf(vals[3]-bf2f(oh.w));
    size_t base = (size_t)samp*NW + 16*q + quad*4;
    *(ushort4*)&Khi[base] = oh;
    *(ushort4*)&Klo[base] = ol;
  }
}

// ---------------- K7: persistent Sinkhorn, warm-started v, stamp/poll barrier ----------------
__global__ __launch_bounds__(256,1) void k_sinkhorn(const ushort* __restrict__ Khi, const ushort* __restrict__ Klo,
                                                    float* __restrict__ plan, float* __restrict__ partials,
                                                    int* __restrict__ stamps, float* __restrict__ vprev,
                                                    float* __restrict__ emus_zero){
  __shared__ __align__(16) float vsh[64];
  __shared__ float tmat[256][33];
  __shared__ float tq[8][64];
  __shared__ float tcol[64];
  __shared__ float mred[4];
  __shared__ float ctrl[1];
  int t = threadIdx.x, b = blockIdx.x;
  int iu = b*256 + t;
  bool active = iu < NU;
  float kr[64];
  if(active){
    const ushort4* kph = (const ushort4*)(Khi + (size_t)iu*NW);
    const ushort4* kpl = (const ushort4*)(Klo + (size_t)iu*NW);
#pragma unroll
    for(int q=0;q<16;q++){
      ushort4 h = kph[q]; ushort4 l = kpl[q];
      kr[4*q+0]=bf2f(h.x)+bf2f(l.x); kr[4*q+1]=bf2f(h.y)+bf2f(l.y);
      kr[4*q+2]=bf2f(h.z)+bf2f(l.z); kr[4*q+3]=bf2f(h.w)+bf2f(l.w);
    }
  } else {
#pragma unroll
    for(int j=0;j<64;j++) kr[j]=0.f;
  }
  if(t < 64) vsh[t] = vprev[t];
  float u = 1.0f, r_old = 0.0f;
  __syncthreads();
  int n = 0;
  while(true){
    // s_i = K_i . v  (fp64 accumulate for residual stability)
    double s = 0.0;
#pragma unroll
    for(int q=0;q<16;q++){
      float4 vv = *(const float4*)&vsh[4*q];
      s += (double)kr[4*q]*vv.x + (double)kr[4*q+1]*vv.y + (double)kr[4*q+2]*vv.z + (double)kr[4*q+3]*vv.w;
    }
    float sf = (float)s;
    float r = u * sf;
    float diff = fabsf(r - r_old);
    float u_new = (active && sf > 0.f) ? 1.0f/sf : 0.0f;
    float wmx = wave_max(diff);
    if((t&63)==0) mred[t>>6] = wmx;
    // column sums of kr[j]*u_new, two 32-wide halves through LDS transpose
#pragma unroll
    for(int h=0;h<2;h++){
#pragma unroll
      for(int jj=0;jj<32;jj++) tmat[t][jj] = kr[32*h+jj]*u_new;
      __syncthreads();
      {
        int j = t & 31, q = t >> 5;
        float ps = 0.f;
#pragma unroll
        for(int rr=0;rr<32;rr++) ps += tmat[q*32+rr][j];
        tq[q][j] = ps;
      }
      __syncthreads();
      if(t < 32) tcol[32*h + t] = tq[0][t]+tq[1][t]+tq[2][t]+tq[3][t]+tq[4][t]+tq[5][t]+tq[6][t]+tq[7][t];
      __syncthreads();
    }
    int buf = n & 1;
    float* P = partials + buf*(SB_NB*66) + b*66;
    if(t < 64){
      __hip_atomic_store(&P[t], tcol[t], __ATOMIC_RELAXED, __HIP_MEMORY_SCOPE_AGENT);
    } else if(t == 64){
      float bm = fmaxf(fmaxf(mred[0],mred[1]), fmaxf(mred[2],mred[3]));
      __hip_atomic_store(&P[64], bm, __ATOMIC_RELAXED, __HIP_MEMORY_SCOPE_AGENT);
    }
    __syncthreads();
    if(t == 0){
      __threadfence();
      __hip_atomic_store(&stamps[b], n+1, __ATOMIC_RELEASE, __HIP_MEMORY_SCOPE_AGENT);
    }
    if(t < SB_NB){
      while(__hip_atomic_load(&stamps[t], __ATOMIC_ACQUIRE, __HIP_MEMORY_SCOPE_AGENT) <= n){}
    }
    __syncthreads();
    // every block redundantly reduces all partials
    {
      int j = t & 63, q4 = t >> 6;
      float ps = 0.f, pm = 0.f;
      const float* PB = partials + buf*(SB_NB*66);
      for(int bb=q4; bb<SB_NB; bb+=4){
        ps += __hip_atomic_load(&PB[bb*66 + j], __ATOMIC_RELAXED, __HIP_MEMORY_SCOPE_AGENT);
        if(j==0) pm = fmaxf(pm, __hip_atomic_load(&PB[bb*66 + 64], __ATOMIC_RELAXED, __HIP_MEMORY_SCOPE_AGENT));
      }
      tq[q4][j] = ps;
      if(j==0) mred[q4] = pm;
    }
    __syncthreads();
    if(t==0) ctrl[0] = fmaxf(fmaxf(mred[0],mred[1]), fmaxf(mred[2],mred[3]));
    __syncthreads();
    float M = ctrl[0];
    if(M <= EPSC || n >= MAXIT) break;   // exit with pre-update u, v
    u = u_new; r_old = r; n++;
    if(t < 64) vsh[t] = (float)NQ / (tq[0][t]+tq[1][t]+tq[2][t]+tq[3][t]);
    __syncthreads();
  }
  if(active){
    float* pp = plan + (size_t)iu*NW;
#pragma unroll
    for(int q=0;q<16;q++){
      float4 o;
      o.x = kr[4*q+0]*u*vsh[4*q+0];
      o.y = kr[4*q+1]*u*vsh[4*q+1];
      o.z = kr[4*q+2]*u*vsh[4*q+2];
      o.w = kr[4*q+3]*u*vsh[4*q+3];
      *(float4*)(pp + 4*q) = o;
    }
  }
  // save converged v for next epoch's warm start
  if(b==0 && t<64) vprev[t] = vsh[t];
  // zero emus (aliases dead Kmat region) for this epoch's k_emus accumulation
  for(int o = b*256 + t; o < NW*DIM; o += SB_NB*256) emus_zero[o] = 0.f;
}

// ---------------- K8: emus accumulation: emus[w,c] += sum_i mask[i,w]*Z[i,c] ----------------
__global__ __launch_bounds__(256) void k_emus(const float* __restrict__ mask, const ushort* __restrict__ Zhi,
                                              const ushort* __restrict__ Zlo, float* __restrict__ emus){
  __shared__ __align__(16) float Msk[64][68];
  __shared__ __align__(16) float Zt[64][68];
  int ct = blockIdx.x, is = blockIdx.y;
  int cb = ct*64;
  int t = threadIdx.x, tr = t & 15, tc = t >> 4;
  float acc[4][4] = {{0}};
  for(int ic=0; ic<20; ic++){
    int ibase = is*1280 + ic*64;
#pragma unroll
    for(int m=0;m<4;m++){
      int e4 = t + 256*m;
      int ii = e4 >> 4, xq = e4 & 15;
      *(float4*)&Msk[ii][4*xq] = *(const float4*)(mask + (size_t)(ibase+ii)*NW + 4*xq);
      size_t zoff = (size_t)(ibase+ii)*DIM + cb + 4*xq;
      ushort4 h = *(const ushort4*)&Zhi[zoff];
      ushort4 l = *(const ushort4*)&Zlo[zoff];
      float4 z;
      z.x = bf2f(h.x)+bf2f(l.x); z.y = bf2f(h.y)+bf2f(l.y);
      z.z = bf2f(h.z)+bf2f(l.z); z.w = bf2f(h.w)+bf2f(l.w);
      *(float4*)&Zt[ii][4*xq] = z;
    }
    __syncthreads();
#pragma unroll
    for(int ii=0;ii<64;ii++){
      float4 aw = *(const float4*)&Msk[ii][4*tr];
      float4 zc = *(const float4*)&Zt[ii][4*tc];
      acc[0][0]+=aw.x*zc.x; acc[0][1]+=aw.x*zc.y; acc[0][2]+=aw.x*zc.z; acc[0][3]+=aw.x*zc.w;
      acc[1][0]+=aw.y*zc.x; acc[1][1]+=aw.y*zc.y; acc[1][2]+=aw.y*zc.z; acc[1][3]+=aw.y*zc.w;
      acc[2][0]+=aw.z*zc.x; acc[2][1]+=aw.z*zc.y; acc[2][2]+=aw.z*zc.z; acc[2][3]+=aw.z*zc.w;
      acc[3][0]+=aw.w*zc.x; acc[3][1]+=aw.w*zc.y; acc[3][2]+=aw.w*zc.z; acc[3][3]+=aw.w*zc.w;
    }
    __syncthreads();
  }
#pragma unroll
  for(int rr=0;rr<4;rr++)
#pragma unroll
    for(int cc=0;cc<4;cc++)
      atomicAdd(&emus[(size_t)(4*tr+rr)*DIM + cb + 4*tc + cc], acc[rr][cc]);
}

// ---------------- K8b: masksum[w] = sum_i mask[i,w] ----------------
__global__ void k_masksum(const float* __restrict__ mask, float* __restrict__ masksum){
  int t = threadIdx.x;
  int w = t & 63, q = t >> 6;
  float s = 0.f;
  for(int rep=0; rep<50; rep++){
    int i = blockIdx.x*200 + rep*4 + q;
    s += mask[(size_t)i*NW + w];
  }
  __shared__ float red[4][64];
  red[q][w] = s;
  __syncthreads();
  if(t < 64) atomicAdd(&masksum[t], red[0][t]+red[1][t]+red[2][t]+red[3][t]);
}

// ---------------- K9: mus update ----------------
__global__ void k_mus_update(float* __restrict__ mus, const float* __restrict__ emus,
                             const float* __restrict__ masksum){
  int idx = blockIdx.x*256 + threadIdx.x;
  int w = idx / DIM;
  float e = emus[idx] / masksum[w];
  mus[idx] += ALPHA * (e - mus[idx]);
}

// ---------------- K10: write P ----------------
__global__ void k_out(const float* __restrict__ mask, const int* __restrict__ labels, float* __restrict__ out){
  int idx = blockIdx.x*256 + threadIdx.x;
  if(idx < NL*NW){
    int i = idx >> 6, w = idx & 63;
    out[idx] = (labels[i]==w) ? 1.0f : 0.0f;
  } else {
    out[idx] = logf(mask[idx]);
  }
}

// ---------------- K11: accuracy partial ----------------
__global__ void k_acc(const float* __restrict__ mask, const int* __restrict__ labels, float* matchcount){
  int iu = blockIdx.x*256 + threadIdx.x;
  float m = 0.f;
  if(iu < NU){
    const float* row = mask + (size_t)(NL+iu)*NW;
    float best = row[0]; int bj = 0;
#pragma unroll
    for(int j=1;j<64;j++){ float v = row[j]; if(v > best){ best = v; bj = j; } }
    m = (labels[NL+iu] == bj) ? 1.f : 0.f;
  }
  float ws = wave_sum(m);
  __shared__ float red[4];
  if((threadIdx.x&63)==0) red[threadIdx.x>>6]=ws;
  __syncthreads();
  if(threadIdx.x==0) atomicAdd(matchcount, red[0]+red[1]+red[2]+red[3]);
}

// ---------------- K12: finalize ----------------
__global__ void k_fin(const float* matchcount, float* __restrict__ out){
  out[(size_t)NTOT*NW]     = (*matchcount) * (1.0f/(float)NU);
  out[(size_t)NTOT*NW + 1] = 0.0f;
}

// ---------------- launch ----------------
extern "C" void kernel_launch(void* const* d_in, const int* in_sizes, int n_in,
                              void* d_out, int out_size, void* d_ws, size_t ws_size,
                              hipStream_t stream){
  const float* X = (const float*)d_in[0];
  const int* labels = (const int*)d_in[1];
  float* out = (float*)d_out;
  float* ws = (float*)d_ws;

  // ws layout (float offsets), total 21,386,816 floats = 85.5 MB
  float*  matchcount = ws + 0;
  float*  munorm     = ws + 4;
  float*  masksum    = ws + 68;
  float*  vprev      = ws + 132;
  float*  csum_l     = ws + 196;
  float*  csum_u     = ws + 1732;
  int*    stamps     = (int*)(ws + 3268);       // 52 ints
  float*  partials   = ws + 3320;               // 2*49*66 = 6468 -> 9788
  float*  mus        = ws + 9792;               // 98304 -> 108096
  ushort* Khi        = (ushort*)(ws + 108096);  // 798720 us = 399360 fl -> 507456
  float*  emus       = ws + 108096;             // ALIAS: first 98304 floats of Khi region
  ushort* Klo        = (ushort*)(ws + 507456);  // -> 906816
  float*  mask       = ws + 906816;             // 819200 -> 1726016
  ushort* Zhi        = (ushort*)(ws + 1726016); // 9830400 fl -> 11556416
  ushort* Zlo        = (ushort*)(ws + 11556416);// -> 21386816
  if(ws_size < (size_t)21386816*4) return;

  // zero scalars, csums, stamps
  hipMemsetAsync(ws, 0, 3320*sizeof(float), stream);

  k_prep<<<3200,256,0,stream>>>(X, Zhi, Zlo);
  k_colsum<<<dim3(3,100),256,0,stream>>>(Zhi, Zlo, csum_l, csum_u);
  k_finalize_means<<<12,256,0,stream>>>(csum_l, csum_u);
  k_center<<<3200,256,0,stream>>>(Zhi, Zlo, csum_l, csum_u);
  k_mus_init<<<64,256,0,stream>>>(Zhi, Zlo, mus);
  k_labeled_mask<<<80,256,0,stream>>>(labels, mask, vprev);

  for(int e=0; e<=EPOCHS; e++){
    k_epoch_prep<<<64,256,0,stream>>>(mus, munorm, masksum, matchcount, stamps);
    k_dist<<<195,256,0,stream>>>(mus, Zhi, Zlo, munorm, Khi, Klo);
    k_sinkhorn<<<SB_NB,256,0,stream>>>(Khi, Klo, mask + NL*NW, partials, stamps, vprev, emus);
    if(e < EPOCHS){
      k_emus<<<dim3(24,10),256,0,stream>>>(mask, Zhi, Zlo, emus);
      k_masksum<<<64,256,0,stream>>>(mask, masksum);
      k_mus_update<<<384,256,0,stream>>>(mus, emus, masksum);
    }
  }
  k_out<<<3200,256,0,stream>>>(mask, labels, out);
  k_acc<<<49,256,0,stream>>>(mask, labels, matchcount);
  k_fin<<<1,1,0,stream>>>(matchcount, out);
}

// Round 3
// 2932.046 us; speedup vs baseline: 1.5853x; 1.1570x over previous
//
#include <hip/hip_runtime.h>
#include <math.h>

#define NW 64
#define NS 5
#define NQ 195
#define DIM 1536
#define NTOT 12800
#define NL 320
#define NU 12480
#define ALPHA 0.2f
#define EPOCHS 20
#define EPSC 1e-6f
#define MAXIT 1000
#define SB_NB 49

typedef float f32x4 __attribute__((ext_vector_type(4)));
typedef short short8 __attribute__((ext_vector_type(8)));

// ---------------- helpers ----------------
__device__ inline float wave_sum(float x){
#pragma unroll
  for(int o=32;o;o>>=1) x += __shfl_xor(x,o);
  return x;
}
__device__ inline float bf2f(ushort h){
  union{uint u; float f;} c; c.u = ((uint)h)<<16; return c.f;
}
__device__ inline ushort f2bf(float x){
  union{float f; uint u;} c; c.f = x;
  uint r = c.u + 0x7FFFu + ((c.u>>16)&1u);
  return (ushort)(r>>16);
}

// ---------------- K1: sqrt power transform + row l2norm -> Zhi bf16 ----------------
__global__ __launch_bounds__(256) void k_prep(const float* __restrict__ X, ushort* __restrict__ Zhi){
  int row = blockIdx.x*4 + (threadIdx.x>>6);
  int lane = threadIdx.x & 63;
  const float4* xp = (const float4*)(X + (size_t)row*DIM);
  float4 v[6]; float ss = 0.f;
#pragma unroll
  for(int q=0;q<6;q++){
    float4 t = xp[lane + 64*q];
    t.x = sqrtf(t.x+1e-6f); t.y = sqrtf(t.y+1e-6f); t.z = sqrtf(t.z+1e-6f); t.w = sqrtf(t.w+1e-6f);
    v[q]=t; ss += t.x*t.x+t.y*t.y+t.z*t.z+t.w*t.w;
  }
  ss = wave_sum(ss);
  float inv = 1.f / fmaxf(sqrtf(ss), 1e-12f);
#pragma unroll
  for(int q=0;q<6;q++){
    float4 t = v[q];
    ushort4 h;
    h.x=f2bf(t.x*inv); h.y=f2bf(t.y*inv); h.z=f2bf(t.z*inv); h.w=f2bf(t.w*inv);
    *(ushort4*)&Zhi[(size_t)row*DIM + 4*lane + 256*q] = h;
  }
}

// ---------------- K2a: segment column sums ----------------
__global__ __launch_bounds__(256) void k_colsum(const ushort* __restrict__ Zhi,
                                                float* __restrict__ csum_l, float* __restrict__ csum_u){
  int c0 = blockIdx.x*512 + 2*threadIdx.x;
  int r0 = blockIdx.y*128;
  float al0=0.f, al1=0.f, au0=0.f, au1=0.f;
  for(int r=r0; r<r0+128; r++){
    ushort2 h = *(const ushort2*)&Zhi[(size_t)r*DIM + c0];
    float x0 = bf2f(h.x), x1 = bf2f(h.y);
    if(r < NL){ al0+=x0; al1+=x1; } else { au0+=x0; au1+=x1; }
  }
  if(r0 < NL){ atomicAdd(&csum_l[c0], al0); atomicAdd(&csum_l[c0+1], al1); }
  if(r0+128 > NL){ atomicAdd(&csum_u[c0], au0); atomicAdd(&csum_u[c0+1], au1); }
}

// ---------------- K2b ----------------
__global__ void k_finalize_means(float* csum_l, float* csum_u){
  int idx = blockIdx.x*256 + threadIdx.x;
  if(idx < DIM) csum_l[idx] *= (1.0f/NL);
  else if(idx < 2*DIM) csum_u[idx-DIM] *= (1.0f/NU);
}

// ---------------- K3: center + row l2norm (in place) ----------------
__global__ __launch_bounds__(256) void k_center(ushort* __restrict__ Zhi,
                                                const float* __restrict__ cm_l, const float* __restrict__ cm_u){
  int row = blockIdx.x*4 + (threadIdx.x>>6);
  int lane = threadIdx.x & 63;
  const float4* cp = (const float4*)((row < NL) ? cm_l : cm_u);
  float4 v[6]; float ss = 0.f;
#pragma unroll
  for(int q=0;q<6;q++){
    ushort4 h = *(const ushort4*)&Zhi[(size_t)row*DIM + 4*lane + 256*q];
    float4 m = cp[lane + 64*q];
    float4 t;
    t.x = bf2f(h.x) - m.x; t.y = bf2f(h.y) - m.y;
    t.z = bf2f(h.z) - m.z; t.w = bf2f(h.w) - m.w;
    v[q]=t; ss += t.x*t.x+t.y*t.y+t.z*t.z+t.w*t.w;
  }
  ss = wave_sum(ss);
  float inv = 1.f / fmaxf(sqrtf(ss), 1e-12f);
#pragma unroll
  for(int q=0;q<6;q++){
    float4 t = v[q];
    ushort4 h;
    h.x=f2bf(t.x*inv); h.y=f2bf(t.y*inv); h.z=f2bf(t.z*inv); h.w=f2bf(t.w*inv);
    *(ushort4*)&Zhi[(size_t)row*DIM + 4*lane + 256*q] = h;
  }
}

// ---------------- K3b: tile-transpose unlabeled Z -> ZT[c][iu] ----------------
__global__ __launch_bounds__(256) void k_ztrans(const ushort* __restrict__ Zhi, ushort* __restrict__ ZT){
  __shared__ ushort T[64][66];
  int ti = blockIdx.x, tc = blockIdx.y;
  int t = threadIdx.x;
  int r = t>>2, ch = (t&3)*16;
  const ushort* src = Zhi + (size_t)(NL + ti*64 + r)*DIM + tc*64 + ch;
  short8 a = *(const short8*)src;
  short8 b = *(const short8*)(src+8);
#pragma unroll
  for(int k=0;k<8;k++){ T[r][ch+k] = (ushort)a[k]; T[r][ch+8+k] = (ushort)b[k]; }
  __syncthreads();
  short8 o0, o1;
#pragma unroll
  for(int k=0;k<8;k++){ o0[k] = (short)T[ch+k][r]; o1[k] = (short)T[ch+8+k][r]; }
  ushort* dst = ZT + (size_t)(tc*64 + r)*NU + ti*64 + ch;
  *(short8*)dst = o0;
  *(short8*)(dst+8) = o1;
}

// ---------------- K4: init mus from labeled shots ----------------
__global__ void k_mus_init(const ushort* __restrict__ Zhi, float* __restrict__ mus){
  int w = blockIdx.x;
#pragma unroll
  for(int q=0;q<6;q++){
    int c = threadIdx.x + 256*q;
    float s = 0.f;
#pragma unroll
    for(int sh=0; sh<NS; sh++) s += bf2f(Zhi[(size_t)(sh*NW + w)*DIM + c]);
    mus[(size_t)w*DIM + c] = s * 0.2f;
  }
}

// ---------------- K4b: vprev = 1 ----------------
__global__ void k_vinit(float* __restrict__ vprev){
  if(threadIdx.x < 64) vprev[threadIdx.x] = 1.0f;
}

// ---------------- K4c: S[c] = 5 * sum_w mus0[w][c] ----------------
__global__ void k_slc(const float* __restrict__ mus, float* __restrict__ S){
  int c = blockIdx.x*256 + threadIdx.x;
  float s = 0.f;
  for(int w=0;w<64;w++) s += mus[(size_t)w*DIM + c];
  S[c] = 5.0f * s;
}

// ---------------- K4d: emus_lab = S[c] + (e-1)*5*mus0 ----------------
__global__ void k_elab(const float* __restrict__ mus, const float* __restrict__ S,
                       float* __restrict__ emus_lab){
  int idx = blockIdx.x*256 + threadIdx.x;
  int c = idx % DIM;
  emus_lab[idx] = S[c] + (expf(1.0f)-1.0f)*5.0f*mus[idx];
}

// ---------------- K5: per-epoch prep ----------------
__global__ void k_epoch_prep(const float* __restrict__ mus, float* munorm, float* masksum,
                             float* matchcount, int* stamps){
  int w = blockIdx.x;
  float ss = 0.f;
#pragma unroll
  for(int q=0;q<6;q++){
    int c = threadIdx.x + 256*q;
    float v = mus[(size_t)w*DIM + c];
    ss += v*v;
  }
  __shared__ float red[4];
  float wsu = wave_sum(ss);
  if((threadIdx.x&63)==0) red[threadIdx.x>>6]=wsu;
  __syncthreads();
  if(threadIdx.x==0){
    munorm[w] = red[0]+red[1]+red[2]+red[3];
    masksum[w] = 315.0f + 5.0f*expf(1.0f);   // labeled contribution (exact)
    if(w==0) *matchcount = 0.f;
    if(w < SB_NB) stamps[w] = 0;
  }
}

// ---------------- K6: dist via MFMA (mus hi/lo x Zhi, 2-pass) -> K bf16 hi/lo ----------------
__global__ __launch_bounds__(256) void k_dist(const float* __restrict__ mus, const ushort* __restrict__ Zhi,
                                              const float* __restrict__ munorm,
                                              ushort* __restrict__ Khi, ushort* __restrict__ Klo){
  __shared__ ushort Ahi[2][64][40];
  __shared__ ushort Alo[2][64][40];
  __shared__ float mn[64];
  int t = threadIdx.x;
  int wv = t>>6, lane = t&63;
  int l15 = lane&15, quad = lane>>4;
  int b = blockIdx.x;
  if(t < 64) mn[t] = munorm[t];
  int sway = t>>2, sj = t&3;
  const float* msrc = mus + (size_t)sway*DIM + sj*8;
  {
    float4 m0 = *(const float4*)(msrc);
    float4 m1 = *(const float4*)(msrc+4);
    float mv[8] = {m0.x,m0.y,m0.z,m0.w,m1.x,m1.y,m1.z,m1.w};
    short8 sh, sl;
#pragma unroll
    for(int i=0;i<8;i++){
      ushort h = f2bf(mv[i]);
      sh[i] = (short)h; sl[i] = (short)f2bf(mv[i]-bf2f(h));
    }
    *(short8*)&Ahi[0][sway][sj*8] = sh;
    *(short8*)&Alo[0][sway][sj*8] = sl;
  }
  int ig = NL + b*64 + wv*16 + l15;
  const ushort* bph = Zhi + (size_t)ig*DIM + quad*8;
  short8 bh = *(const short8*)bph;
  f32x4 acc[4];
#pragma unroll
  for(int q=0;q<4;q++) acc[q] = (f32x4){0.f,0.f,0.f,0.f};
  __syncthreads();
  for(int kt=0; kt<48; kt++){
    int buf = kt&1;
    short8 bh_n = bh;
    if(kt < 47){
      bh_n = *(const short8*)(bph + (kt+1)*32);
      const float* ms = msrc + (kt+1)*32;
      float4 m0 = *(const float4*)(ms);
      float4 m1 = *(const float4*)(ms+4);
      float mv[8] = {m0.x,m0.y,m0.z,m0.w,m1.x,m1.y,m1.z,m1.w};
      short8 sh, sl;
#pragma unroll
      for(int i=0;i<8;i++){
        ushort h = f2bf(mv[i]);
        sh[i] = (short)h; sl[i] = (short)f2bf(mv[i]-bf2f(h));
      }
      *(short8*)&Ahi[buf^1][sway][sj*8] = sh;
      *(short8*)&Alo[buf^1][sway][sj*8] = sl;
    }
#pragma unroll
    for(int q=0;q<4;q++){
      short8 ah = *(const short8*)&Ahi[buf][16*q + l15][quad*8];
      short8 al = *(const short8*)&Alo[buf][16*q + l15][quad*8];
      acc[q] = __builtin_amdgcn_mfma_f32_16x16x32_bf16(ah, bh, acc[q], 0,0,0);
      acc[q] = __builtin_amdgcn_mfma_f32_16x16x32_bf16(al, bh, acc[q], 0,0,0);
    }
    __syncthreads();
    bh = bh_n;
  }
  int samp = b*64 + wv*16 + l15;
#pragma unroll
  for(int q=0;q<4;q++){
    float vals[4];
#pragma unroll
    for(int rg=0;rg<4;rg++){
      int w = 16*q + quad*4 + rg;
      float d2 = 1.0f + mn[w] - 2.0f*acc[q][rg];
      vals[rg] = expf(-10.0f * sqrtf(fmaxf(d2, 0.0f)));
    }
    ushort4 oh, ol;
    oh.x=f2bf(vals[0]); ol.x=f2bf(vals[0]-bf2f(oh.x));
    oh.y=f2bf(vals[1]); ol.y=f2bf(vals[1]-bf2f(oh.y));
    oh.z=f2bf(vals[2]); ol.z=f2bf(vals[2]-bf2f(oh.z));
    oh.w=f2bf(vals[3]); ol.w=f2bf(vals[3]-bf2f(oh.w));
    size_t base = (size_t)samp*NW + 16*q + quad*4;
    *(ushort4*)&Khi[base] = oh;
    *(ushort4*)&Klo[base] = ol;
  }
}

// ---------------- K7: persistent Sinkhorn -> plan^T bf16 hi/lo + masksum colsums ----------------
__global__ __launch_bounds__(256,1) void k_sinkhorn(const ushort* __restrict__ Khi, const ushort* __restrict__ Klo,
                                                    ushort* __restrict__ MThi, ushort* __restrict__ MTlo,
                                                    float* __restrict__ partials, int* __restrict__ stamps,
                                                    float* __restrict__ vprev, float* __restrict__ masksum){
  __shared__ __align__(16) float vsh[64];
  __shared__ float tmat[256][33];
  __shared__ float tq[8][64];
  __shared__ float tcol[64];
  __shared__ float mred[4];
  __shared__ float ctrl[1];
  int t = threadIdx.x, b = blockIdx.x;
  int iu = b*256 + t;
  bool active = iu < NU;
  float kr[64];
  if(active){
    const ushort4* kph = (const ushort4*)(Khi + (size_t)iu*NW);
    const ushort4* kpl = (const ushort4*)(Klo + (size_t)iu*NW);
#pragma unroll
    for(int q=0;q<16;q++){
      ushort4 h = kph[q]; ushort4 l = kpl[q];
      kr[4*q+0]=bf2f(h.x)+bf2f(l.x); kr[4*q+1]=bf2f(h.y)+bf2f(l.y);
      kr[4*q+2]=bf2f(h.z)+bf2f(l.z); kr[4*q+3]=bf2f(h.w)+bf2f(l.w);
    }
  } else {
#pragma unroll
    for(int j=0;j<64;j++) kr[j]=0.f;
  }
  if(t < 64) vsh[t] = vprev[t];
  float u = 1.0f, r_old = 0.0f;
  __syncthreads();
  int n = 0;
  while(true){
    float s = 0.f;
#pragma unroll
    for(int q=0;q<16;q++){
      float4 vv = *(const float4*)&vsh[4*q];
      s += kr[4*q]*vv.x + kr[4*q+1]*vv.y + kr[4*q+2]*vv.z + kr[4*q+3]*vv.w;
    }
    float r = u * s;
    float diff = fabsf(r - r_old);
    float u_new = (active && s > 0.f) ? 1.0f/s : 0.0f;
    {
      float wmx = diff;
#pragma unroll
      for(int o=32;o;o>>=1) wmx = fmaxf(wmx, __shfl_xor(wmx,o));
      if((t&63)==0) mred[t>>6] = wmx;
    }
#pragma unroll
    for(int h=0;h<2;h++){
#pragma unroll
      for(int jj=0;jj<32;jj++) tmat[t][jj] = kr[32*h+jj]*u_new;
      __syncthreads();
      {
        int j = t & 31, q = t >> 5;
        float ps = 0.f;
#pragma unroll
        for(int rr=0;rr<32;rr++) ps += tmat[q*32+rr][j];
        tq[q][j] = ps;
      }
      __syncthreads();
      if(t < 32) tcol[32*h + t] = tq[0][t]+tq[1][t]+tq[2][t]+tq[3][t]+tq[4][t]+tq[5][t]+tq[6][t]+tq[7][t];
      __syncthreads();
    }
    int buf = n & 1;
    float* P = partials + buf*(SB_NB*66) + b*66;
    if(t < 64){
      __hip_atomic_store(&P[t], tcol[t], __ATOMIC_RELAXED, __HIP_MEMORY_SCOPE_AGENT);
    } else if(t == 64){
      float bm = fmaxf(fmaxf(mred[0],mred[1]), fmaxf(mred[2],mred[3]));
      __hip_atomic_store(&P[64], bm, __ATOMIC_RELAXED, __HIP_MEMORY_SCOPE_AGENT);
    }
    __syncthreads();
    if(t == 0){
      __threadfence();
      __hip_atomic_store(&stamps[b], n+1, __ATOMIC_RELEASE, __HIP_MEMORY_SCOPE_AGENT);
    }
    if(t < SB_NB){
      while(__hip_atomic_load(&stamps[t], __ATOMIC_ACQUIRE, __HIP_MEMORY_SCOPE_AGENT) <= n){}
    }
    __syncthreads();
    {
      int j = t & 63, q4 = t >> 6;
      float ps = 0.f, pm = 0.f;
      const float* PB = partials + buf*(SB_NB*66);
      for(int bb=q4; bb<SB_NB; bb+=4){
        ps += __hip_atomic_load(&PB[bb*66 + j], __ATOMIC_RELAXED, __HIP_MEMORY_SCOPE_AGENT);
        if(j==0) pm = fmaxf(pm, __hip_atomic_load(&PB[bb*66 + 64], __ATOMIC_RELAXED, __HIP_MEMORY_SCOPE_AGENT));
      }
      tq[q4][j] = ps;
      if(j==0) mred[q4] = pm;
    }
    __syncthreads();
    if(t==0) ctrl[0] = fmaxf(fmaxf(mred[0],mred[1]), fmaxf(mred[2],mred[3]));
    __syncthreads();
    float M = ctrl[0];
    if(M <= EPSC || n >= MAXIT) break;
    u = u_new; r_old = r; n++;
    if(t < 64) vsh[t] = (float)NQ / (tq[0][t]+tq[1][t]+tq[2][t]+tq[3][t]);
    __syncthreads();
  }
  // final plan colsums -> masksum: colsum_j = v_j * sum_i kr[i][j]*u
#pragma unroll
  for(int h=0;h<2;h++){
#pragma unroll
    for(int jj=0;jj<32;jj++) tmat[t][jj] = kr[32*h+jj]*u;
    __syncthreads();
    {
      int j = t & 31, q = t >> 5;
      float ps = 0.f;
#pragma unroll
      for(int rr=0;rr<32;rr++) ps += tmat[q*32+rr][j];
      tq[q][j] = ps;
    }
    __syncthreads();
    if(t < 32) tcol[32*h + t] = tq[0][t]+tq[1][t]+tq[2][t]+tq[3][t]+tq[4][t]+tq[5][t]+tq[6][t]+tq[7][t];
    __syncthreads();
  }
  if(t < 64) atomicAdd(&masksum[t], tcol[t]*vsh[t]);
  // store plan transposed, bf16 hi/lo (coalesced across lanes per w)
  if(active){
#pragma unroll
    for(int j=0;j<64;j++){
      float val = kr[j]*u*vsh[j];
      ushort h = f2bf(val);
      MThi[(size_t)j*NU + iu] = h;
      MTlo[(size_t)j*NU + iu] = f2bf(val - bf2f(h));
    }
  }
  if(b==0 && t<64) vprev[t] = vsh[t];
}

// ---------------- K8: emus via MFMA: part[s][w][c] = sum_i plan^T[w][i] * ZT[c][i] ----------------
// grid (96 c-tiles of 16, 8 i-segments), 64 threads (one wave). No LDS.
__global__ __launch_bounds__(64) void k_emus(const ushort* __restrict__ MThi, const ushort* __restrict__ MTlo,
                                             const ushort* __restrict__ ZThi, float* __restrict__ part){
  int t = threadIdx.x, l15 = t&15, quad = t>>4;
  int cx = blockIdx.x, iy = blockIdx.y;
  int start = iy*1568;
  int cnt = (NU - start < 1568 ? NU - start : 1568) >> 5;
  const ushort* ap[4]; const ushort* alp[4];
#pragma unroll
  for(int q=0;q<4;q++){
    ap[q]  = MThi + (size_t)(16*q + l15)*NU + start + quad*8;
    alp[q] = MTlo + (size_t)(16*q + l15)*NU + start + quad*8;
  }
  const ushort* bp = ZThi + (size_t)(cx*16 + l15)*NU + start + quad*8;
  f32x4 acc[4];
#pragma unroll
  for(int q=0;q<4;q++) acc[q] = (f32x4){0.f,0.f,0.f,0.f};
  short8 ah[4], al[4], bh;
#pragma unroll
  for(int q=0;q<4;q++){ ah[q] = *(const short8*)ap[q]; al[q] = *(const short8*)alp[q]; }
  bh = *(const short8*)bp;
  for(int kt=0; kt<cnt; kt++){
    short8 nah[4], nal[4], nbh;
    if(kt+1 < cnt){
      int off = (kt+1)*32;
#pragma unroll
      for(int q=0;q<4;q++){ nah[q] = *(const short8*)(ap[q]+off); nal[q] = *(const short8*)(alp[q]+off); }
      nbh = *(const short8*)(bp+off);
    }
#pragma unroll
    for(int q=0;q<4;q++){
      acc[q] = __builtin_amdgcn_mfma_f32_16x16x32_bf16(ah[q], bh, acc[q], 0,0,0);
      acc[q] = __builtin_amdgcn_mfma_f32_16x16x32_bf16(al[q], bh, acc[q], 0,0,0);
    }
    if(kt+1 < cnt){
#pragma unroll
      for(int q=0;q<4;q++){ ah[q]=nah[q]; al[q]=nal[q]; }
      bh = nbh;
    }
  }
  float* dst = part + (size_t)iy*(NW*DIM);
#pragma unroll
  for(int q=0;q<4;q++)
#pragma unroll
    for(int rg=0;rg<4;rg++)
      dst[(size_t)(16*q + quad*4 + rg)*DIM + cx*16 + l15] = acc[q][rg];
}

// ---------------- K9: mus update (sums 8 partials + labeled const) ----------------
__global__ void k_mus_update(float* __restrict__ mus, const float* __restrict__ emus_lab,
                             const float* __restrict__ part, const float* __restrict__ masksum){
  int idx = blockIdx.x*256 + threadIdx.x;
  int w = idx / DIM;
  float e = emus_lab[idx];
#pragma unroll
  for(int s=0;s<8;s++) e += part[(size_t)s*(NW*DIM) + idx];
  e /= masksum[w];
  mus[idx] += ALPHA * (e - mus[idx]);
}

// ---------------- K10a: labeled onehot rows ----------------
__global__ void k_out_lab(const int* __restrict__ labels, float* __restrict__ out){
  int idx = blockIdx.x*256 + threadIdx.x;
  if(idx < NL*NW){
    int i = idx >> 6, w = idx & 63;
    out[idx] = (labels[i]==w) ? 1.0f : 0.0f;
  }
}

// ---------------- K10b: unlabeled rows: out = log(plan), via LDS tile transpose ----------------
__global__ __launch_bounds__(256) void k_out_u(const ushort* __restrict__ MThi, const ushort* __restrict__ MTlo,
                                               float* __restrict__ out){
  __shared__ float P[64][68];
  int b = blockIdx.x;
  int iu0 = b*64;
  int t = threadIdx.x;
  int w = t>>2, ch = (t&3)*16;
  const ushort* ph = MThi + (size_t)w*NU + iu0 + ch;
  const ushort* pl = MTlo + (size_t)w*NU + iu0 + ch;
  short8 h0 = *(const short8*)ph, h1 = *(const short8*)(ph+8);
  short8 l0 = *(const short8*)pl, l1 = *(const short8*)(pl+8);
#pragma unroll
  for(int k=0;k<8;k++){
    P[ch+k][w]   = logf(bf2f((ushort)h0[k]) + bf2f((ushort)l0[k]));
    P[ch+8+k][w] = logf(bf2f((ushort)h1[k]) + bf2f((ushort)l1[k]));
  }
  __syncthreads();
  int r = t>>2, c0 = (t&3)*16;
  float4* dst = (float4*)(out + (size_t)(NL + iu0 + r)*NW + c0);
#pragma unroll
  for(int g=0;g<4;g++) dst[g] = *(float4*)&P[r][c0+4*g];
}

// ---------------- K11: accuracy ----------------
__global__ void k_acc(const ushort* __restrict__ MThi, const ushort* __restrict__ MTlo,
                      const int* __restrict__ labels, float* matchcount){
  int iu = blockIdx.x*256 + threadIdx.x;
  float m = 0.f;
  if(iu < NU){
    float best = -1.f; int bj = 0;
#pragma unroll 8
    for(int w=0;w<64;w++){
      float v = bf2f(MThi[(size_t)w*NU + iu]) + bf2f(MTlo[(size_t)w*NU + iu]);
      if(v > best){ best = v; bj = w; }
    }
    m = (labels[NL+iu] == bj) ? 1.f : 0.f;
  }
  float ws = wave_sum(m);
  __shared__ float red[4];
  if((threadIdx.x&63)==0) red[threadIdx.x>>6]=ws;
  __syncthreads();
  if(threadIdx.x==0) atomicAdd(matchcount, red[0]+red[1]+red[2]+red[3]);
}

// ---------------- K12 ----------------
__global__ void k_fin(const float* matchcount, float* __restrict__ out){
  out[(size_t)NTOT*NW]     = (*matchcount) * (1.0f/(float)NU);
  out[(size_t)NTOT*NW + 1] = 0.0f;
}

// ---------------- launch ----------------
extern "C" void kernel_launch(void* const* d_in, const int* in_sizes, int n_in,
                              void* d_out, int out_size, void* d_ws, size_t ws_size,
                              hipStream_t stream){
  const float* X = (const float*)d_in[0];
  const int* labels = (const int*)d_in[1];
  float* out = (float*)d_out;
  float* ws = (float*)d_ws;

  // ws layout (float offsets), total 21,220,424 fl = 84.88 MB (< proven-safe 85.94 MB)
  float*  matchcount = ws + 0;
  float*  munorm     = ws + 4;
  float*  masksum    = ws + 68;
  float*  vprev      = ws + 132;
  float*  csum_l     = ws + 196;
  float*  csum_u     = ws + 1732;
  int*    stamps     = (int*)(ws + 3268);        // 64 ints
  float*  partials   = ws + 3332;                // 2*49*66 -> 9800
  float*  Slc        = ws + 9800;                // 1536 -> 11336
  float*  mus        = ws + 11336;               // 98304 -> 109640
  float*  emus_lab   = ws + 109640;              // 98304 -> 207944
  ushort* Khi        = (ushort*)(ws + 207944);   // 798720 us -> 607304
  float*  part       = ws + 207944;              // ALIAS of Khi/Klo (dead when k_emus runs): 8*98304=786432 fl
  ushort* Klo        = (ushort*)(ws + 607304);   // -> 1006664
  ushort* MThi       = (ushort*)(ws + 1006664);  // -> 1406024
  ushort* MTlo       = (ushort*)(ws + 1406024);  // -> 1805384
  ushort* Zhi        = (ushort*)(ws + 1805384);  // 19660800 us -> 11635784
  ushort* ZThi       = (ushort*)(ws + 11635784); // 19169280 us -> 21220424
  if(ws_size < (size_t)21220424*4) return;

  hipMemsetAsync(ws, 0, 3332*sizeof(float), stream);

  k_prep<<<3200,256,0,stream>>>(X, Zhi);
  k_colsum<<<dim3(3,100),256,0,stream>>>(Zhi, csum_l, csum_u);
  k_finalize_means<<<12,256,0,stream>>>(csum_l, csum_u);
  k_center<<<3200,256,0,stream>>>(Zhi, csum_l, csum_u);
  k_ztrans<<<dim3(195,24),256,0,stream>>>(Zhi, ZThi);
  k_mus_init<<<64,256,0,stream>>>(Zhi, mus);
  k_vinit<<<1,64,0,stream>>>(vprev);
  k_slc<<<6,256,0,stream>>>(mus, Slc);
  k_elab<<<384,256,0,stream>>>(mus, Slc, emus_lab);

  for(int e=0; e<=EPOCHS; e++){
    k_epoch_prep<<<64,256,0,stream>>>(mus, munorm, masksum, matchcount, stamps);
    k_dist<<<195,256,0,stream>>>(mus, Zhi, munorm, Khi, Klo);
    k_sinkhorn<<<SB_NB,256,0,stream>>>(Khi, Klo, MThi, MTlo, partials, stamps, vprev, masksum);
    if(e < EPOCHS){
      k_emus<<<dim3(96,8),64,0,stream>>>(MThi, MTlo, ZThi, part);
      k_mus_update<<<384,256,0,stream>>>(mus, emus_lab, part, masksum);
    }
  }
  k_out_lab<<<80,256,0,stream>>>(labels, out);
  k_out_u<<<195,256,0,stream>>>(MThi, MTlo, out);
  k_acc<<<49,256,0,stream>>>(MThi, MTlo, labels, matchcount);
  k_fin<<<1,1,0,stream>>>(matchcount, out);
}

// Round 4
// 2722.458 us; speedup vs baseline: 1.7074x; 1.0770x over previous
//
#include <hip/hip_runtime.h>
#include <math.h>

#define NW 64
#define NS 5
#define NQ 195
#define DIM 1536
#define NTOT 12800
#define NL 320
#define NU 12480
#define NUP 12544
#define ALPHA 0.2f
#define EPOCHS 20
#define EPSC 1e-6f
#define MAXIT 1000
#define SB_NB 49

typedef float f32x4 __attribute__((ext_vector_type(4)));
typedef short short8 __attribute__((ext_vector_type(8)));

// ---------------- helpers ----------------
__device__ inline float wave_sum(float x){
#pragma unroll
  for(int o=32;o;o>>=1) x += __shfl_xor(x,o);
  return x;
}
__device__ inline float bf2f(ushort h){
  union{uint u; float f;} c; c.u = ((uint)h)<<16; return c.f;
}
__device__ inline ushort f2bf(float x){
  union{float f; uint u;} c; c.f = x;
  uint r = c.u + 0x7FFFu + ((c.u>>16)&1u);
  return (ushort)(r>>16);
}

// ---------------- K1: sqrt power transform + row l2norm -> Zhi bf16 ----------------
__global__ __launch_bounds__(256) void k_prep(const float* __restrict__ X, ushort* __restrict__ Zhi){
  int row = blockIdx.x*4 + (threadIdx.x>>6);
  int lane = threadIdx.x & 63;
  const float4* xp = (const float4*)(X + (size_t)row*DIM);
  float4 v[6]; float ss = 0.f;
#pragma unroll
  for(int q=0;q<6;q++){
    float4 t = xp[lane + 64*q];
    t.x = sqrtf(t.x+1e-6f); t.y = sqrtf(t.y+1e-6f); t.z = sqrtf(t.z+1e-6f); t.w = sqrtf(t.w+1e-6f);
    v[q]=t; ss += t.x*t.x+t.y*t.y+t.z*t.z+t.w*t.w;
  }
  ss = wave_sum(ss);
  float inv = 1.f / fmaxf(sqrtf(ss), 1e-12f);
#pragma unroll
  for(int q=0;q<6;q++){
    float4 t = v[q];
    ushort4 h;
    h.x=f2bf(t.x*inv); h.y=f2bf(t.y*inv); h.z=f2bf(t.z*inv); h.w=f2bf(t.w*inv);
    *(ushort4*)&Zhi[(size_t)row*DIM + 4*lane + 256*q] = h;
  }
}

// ---------------- K2a: segment column sums ----------------
__global__ __launch_bounds__(256) void k_colsum(const ushort* __restrict__ Zhi,
                                                float* __restrict__ csum_l, float* __restrict__ csum_u){
  int c0 = blockIdx.x*512 + 2*threadIdx.x;
  int r0 = blockIdx.y*128;
  float al0=0.f, al1=0.f, au0=0.f, au1=0.f;
  for(int r=r0; r<r0+128; r++){
    ushort2 h = *(const ushort2*)&Zhi[(size_t)r*DIM + c0];
    float x0 = bf2f(h.x), x1 = bf2f(h.y);
    if(r < NL){ al0+=x0; al1+=x1; } else { au0+=x0; au1+=x1; }
  }
  if(r0 < NL){ atomicAdd(&csum_l[c0], al0); atomicAdd(&csum_l[c0+1], al1); }
  if(r0+128 > NL){ atomicAdd(&csum_u[c0], au0); atomicAdd(&csum_u[c0+1], au1); }
}

// ---------------- K2b ----------------
__global__ void k_finalize_means(float* csum_l, float* csum_u){
  int idx = blockIdx.x*256 + threadIdx.x;
  if(idx < DIM) csum_l[idx] *= (1.0f/NL);
  else if(idx < 2*DIM) csum_u[idx-DIM] *= (1.0f/NU);
}

// ---------------- K3: center + row l2norm (in place) ----------------
__global__ __launch_bounds__(256) void k_center(ushort* __restrict__ Zhi,
                                                const float* __restrict__ cm_l, const float* __restrict__ cm_u){
  int row = blockIdx.x*4 + (threadIdx.x>>6);
  int lane = threadIdx.x & 63;
  const float4* cp = (const float4*)((row < NL) ? cm_l : cm_u);
  float4 v[6]; float ss = 0.f;
#pragma unroll
  for(int q=0;q<6;q++){
    ushort4 h = *(const ushort4*)&Zhi[(size_t)row*DIM + 4*lane + 256*q];
    float4 m = cp[lane + 64*q];
    float4 t;
    t.x = bf2f(h.x) - m.x; t.y = bf2f(h.y) - m.y;
    t.z = bf2f(h.z) - m.z; t.w = bf2f(h.w) - m.w;
    v[q]=t; ss += t.x*t.x+t.y*t.y+t.z*t.z+t.w*t.w;
  }
  ss = wave_sum(ss);
  float inv = 1.f / fmaxf(sqrtf(ss), 1e-12f);
#pragma unroll
  for(int q=0;q<6;q++){
    float4 t = v[q];
    ushort4 h;
    h.x=f2bf(t.x*inv); h.y=f2bf(t.y*inv); h.z=f2bf(t.z*inv); h.w=f2bf(t.w*inv);
    *(ushort4*)&Zhi[(size_t)row*DIM + 4*lane + 256*q] = h;
  }
}

// ---------------- K3b: tile-transpose unlabeled Z -> ZT[c][iu] (pitch NUP) ----------------
__global__ __launch_bounds__(256) void k_ztrans(const ushort* __restrict__ Zhi, ushort* __restrict__ ZT){
  __shared__ ushort T[64][66];
  int ti = blockIdx.x, tc = blockIdx.y;
  int t = threadIdx.x;
  int r = t>>2, ch = (t&3)*16;
  const ushort* src = Zhi + (size_t)(NL + ti*64 + r)*DIM + tc*64 + ch;
  short8 a = *(const short8*)src;
  short8 b = *(const short8*)(src+8);
#pragma unroll
  for(int k=0;k<8;k++){ T[r][ch+k] = (ushort)a[k]; T[r][ch+8+k] = (ushort)b[k]; }
  __syncthreads();
  short8 o0, o1;
#pragma unroll
  for(int k=0;k<8;k++){ o0[k] = (short)T[ch+k][r]; o1[k] = (short)T[ch+8+k][r]; }
  ushort* dst = ZT + (size_t)(tc*64 + r)*NUP + ti*64 + ch;
  *(short8*)dst = o0;
  *(short8*)(dst+8) = o1;
}

// ---------------- K3c: zero ZT pad cols [NU, NUP) ----------------
__global__ void k_ztpad(ushort* __restrict__ ZT){
  int idx = blockIdx.x*256 + threadIdx.x;   // < 1536*64
  int c = idx >> 6, j = idx & 63;
  if(c < DIM) ZT[(size_t)c*NUP + NU + j] = 0;
}

// ---------------- K4: init mus from labeled shots ----------------
__global__ void k_mus_init(const ushort* __restrict__ Zhi, float* __restrict__ mus){
  int w = blockIdx.x;
#pragma unroll
  for(int q=0;q<6;q++){
    int c = threadIdx.x + 256*q;
    float s = 0.f;
#pragma unroll
    for(int sh=0; sh<NS; sh++) s += bf2f(Zhi[(size_t)(sh*NW + w)*DIM + c]);
    mus[(size_t)w*DIM + c] = s * 0.2f;
  }
}

// ---------------- K4b: vprev = 1 ----------------
__global__ void k_vinit(float* __restrict__ vprev){
  if(threadIdx.x < 64) vprev[threadIdx.x] = 1.0f;
}

// ---------------- K4c: S[c] = 5 * sum_w mus0[w][c] ----------------
__global__ void k_slc(const float* __restrict__ mus, float* __restrict__ S){
  int c = blockIdx.x*256 + threadIdx.x;
  float s = 0.f;
  for(int w=0;w<64;w++) s += mus[(size_t)w*DIM + c];
  S[c] = 5.0f * s;
}

// ---------------- K4d: emus_lab = S[c] + (e-1)*5*mus0 ----------------
__global__ void k_elab(const float* __restrict__ mus, const float* __restrict__ S,
                       float* __restrict__ emus_lab){
  int idx = blockIdx.x*256 + threadIdx.x;
  int c = idx % DIM;
  emus_lab[idx] = S[c] + (expf(1.0f)-1.0f)*5.0f*mus[idx];
}

// ---------------- K5: per-epoch prep: munorm, masksum, stamps, mus->bf16 hi/lo ----------------
__global__ void k_epoch_prep(const float* __restrict__ mus, float* munorm, float* masksum,
                             float* matchcount, int* stamps,
                             ushort* __restrict__ mbh, ushort* __restrict__ mbl){
  int w = blockIdx.x;
  float ss = 0.f;
#pragma unroll
  for(int q=0;q<6;q++){
    int c = threadIdx.x + 256*q;
    float v = mus[(size_t)w*DIM + c];
    ss += v*v;
    ushort h = f2bf(v);
    mbh[(size_t)w*DIM + c] = h;
    mbl[(size_t)w*DIM + c] = f2bf(v - bf2f(h));
  }
  __shared__ float red[4];
  float wsu = wave_sum(ss);
  if((threadIdx.x&63)==0) red[threadIdx.x>>6]=wsu;
  __syncthreads();
  if(threadIdx.x==0){
    munorm[w] = red[0]+red[1]+red[2]+red[3];
    masksum[w] = 315.0f + 5.0f*expf(1.0f);
    if(w==0) *matchcount = 0.f;
    if(w < SB_NB) stamps[w] = 0;
  }
}

// ---------------- K6: dist via MFMA, no LDS, depth-2 prefetch -> Kmat fp32 ----------------
// grid 780 x 64: wave = 16 samples x 64 ways, k over 1536 (48 steps of 32)
__global__ __launch_bounds__(64) void k_dist(const ushort* __restrict__ mbh, const ushort* __restrict__ mbl,
                                             const ushort* __restrict__ Zhi, const float* __restrict__ munorm,
                                             float* __restrict__ Kmat){
  int t = threadIdx.x, l15 = t&15, quad = t>>4;
  int b = blockIdx.x;
  const ushort* ap = Zhi + (size_t)(NL + b*16 + l15)*DIM + quad*8;
  const ushort* bhp[4]; const ushort* blp[4];
#pragma unroll
  for(int q=0;q<4;q++){
    bhp[q] = mbh + (size_t)(16*q + l15)*DIM + quad*8;
    blp[q] = mbl + (size_t)(16*q + l15)*DIM + quad*8;
  }
  f32x4 acc[4];
#pragma unroll
  for(int q=0;q<4;q++) acc[q] = (f32x4){0.f,0.f,0.f,0.f};
  short8 abuf[3], hbuf[3][4], lbuf[3][4];
#pragma unroll
  for(int s=0;s<2;s++){
    abuf[s] = *(const short8*)(ap + s*32);
#pragma unroll
    for(int q=0;q<4;q++){
      hbuf[s][q] = *(const short8*)(bhp[q] + s*32);
      lbuf[s][q] = *(const short8*)(blp[q] + s*32);
    }
  }
#pragma unroll
  for(int kt=0; kt<48; kt++){
    int cur = kt%3, nx = (kt+2)%3;
    if(kt+2 < 48){
      abuf[nx] = *(const short8*)(ap + (kt+2)*32);
#pragma unroll
      for(int q=0;q<4;q++){
        hbuf[nx][q] = *(const short8*)(bhp[q] + (kt+2)*32);
        lbuf[nx][q] = *(const short8*)(blp[q] + (kt+2)*32);
      }
    }
#pragma unroll
    for(int q=0;q<4;q++){
      acc[q] = __builtin_amdgcn_mfma_f32_16x16x32_bf16(abuf[cur], hbuf[cur][q], acc[q], 0,0,0);
      acc[q] = __builtin_amdgcn_mfma_f32_16x16x32_bf16(abuf[cur], lbuf[cur][q], acc[q], 0,0,0);
    }
  }
  int samp0 = b*16 + quad*4;
#pragma unroll
  for(int q=0;q<4;q++){
    int w = 16*q + l15;
    float mn = munorm[w];
#pragma unroll
    for(int rg=0;rg<4;rg++){
      float d2 = 1.0f + mn - 2.0f*acc[q][rg];
      Kmat[(size_t)(samp0+rg)*NW + w] = expf(-10.0f * sqrtf(fmaxf(d2, 0.0f)));
    }
  }
}

// ---------------- K7: persistent Sinkhorn -> plan^T bf16 hi/lo + masksum colsums ----------------
__global__ __launch_bounds__(256,1) void k_sinkhorn(const float* __restrict__ Kmat,
                                                    ushort* __restrict__ MThi, ushort* __restrict__ MTlo,
                                                    float* __restrict__ partials, int* __restrict__ stamps,
                                                    float* __restrict__ vprev, float* __restrict__ masksum){
  __shared__ __align__(16) float vsh[64];
  __shared__ float tmat[256][33];
  __shared__ float tq[8][64];
  __shared__ float tcol[64];
  __shared__ float mred[4];
  __shared__ float ctrl[1];
  int t = threadIdx.x, b = blockIdx.x;
  int iu = b*256 + t;
  bool active = iu < NU;
  float kr[64];
  if(active){
    const float4* kp = (const float4*)(Kmat + (size_t)iu*NW);
#pragma unroll
    for(int q=0;q<16;q++){
      float4 x = kp[q];
      kr[4*q]=x.x; kr[4*q+1]=x.y; kr[4*q+2]=x.z; kr[4*q+3]=x.w;
    }
  } else {
#pragma unroll
    for(int j=0;j<64;j++) kr[j]=0.f;
  }
  if(t < 64) vsh[t] = vprev[t];
  float u = 1.0f, r_old = 0.0f;
  __syncthreads();
  int n = 0;
  while(true){
    float s = 0.f;
#pragma unroll
    for(int q=0;q<16;q++){
      float4 vv = *(const float4*)&vsh[4*q];
      s += kr[4*q]*vv.x + kr[4*q+1]*vv.y + kr[4*q+2]*vv.z + kr[4*q+3]*vv.w;
    }
    float r = u * s;
    float diff = fabsf(r - r_old);
    float u_new = (active && s > 0.f) ? 1.0f/s : 0.0f;
    {
      float wmx = diff;
#pragma unroll
      for(int o=32;o;o>>=1) wmx = fmaxf(wmx, __shfl_xor(wmx,o));
      if((t&63)==0) mred[t>>6] = wmx;
    }
#pragma unroll
    for(int h=0;h<2;h++){
#pragma unroll
      for(int jj=0;jj<32;jj++) tmat[t][jj] = kr[32*h+jj]*u_new;
      __syncthreads();
      {
        int j = t & 31, q = t >> 5;
        float ps = 0.f;
#pragma unroll
        for(int rr=0;rr<32;rr++) ps += tmat[q*32+rr][j];
        tq[q][j] = ps;
      }
      __syncthreads();
      if(t < 32) tcol[32*h + t] = tq[0][t]+tq[1][t]+tq[2][t]+tq[3][t]+tq[4][t]+tq[5][t]+tq[6][t]+tq[7][t];
      __syncthreads();
    }
    int buf = n & 1;
    float* P = partials + buf*(SB_NB*66) + b*66;
    if(t < 64){
      __hip_atomic_store(&P[t], tcol[t], __ATOMIC_RELAXED, __HIP_MEMORY_SCOPE_AGENT);
    } else if(t == 64){
      float bm = fmaxf(fmaxf(mred[0],mred[1]), fmaxf(mred[2],mred[3]));
      __hip_atomic_store(&P[64], bm, __ATOMIC_RELAXED, __HIP_MEMORY_SCOPE_AGENT);
    }
    __syncthreads();
    if(t == 0){
      __threadfence();
      __hip_atomic_store(&stamps[b], n+1, __ATOMIC_RELEASE, __HIP_MEMORY_SCOPE_AGENT);
    }
    if(t < SB_NB){
      while(__hip_atomic_load(&stamps[t], __ATOMIC_ACQUIRE, __HIP_MEMORY_SCOPE_AGENT) <= n){}
    }
    __syncthreads();
    {
      int j = t & 63, q4 = t >> 6;
      float ps = 0.f, pm = 0.f;
      const float* PB = partials + buf*(SB_NB*66);
      for(int bb=q4; bb<SB_NB; bb+=4){
        ps += __hip_atomic_load(&PB[bb*66 + j], __ATOMIC_RELAXED, __HIP_MEMORY_SCOPE_AGENT);
        if(j==0) pm = fmaxf(pm, __hip_atomic_load(&PB[bb*66 + 64], __ATOMIC_RELAXED, __HIP_MEMORY_SCOPE_AGENT));
      }
      tq[q4][j] = ps;
      if(j==0) mred[q4] = pm;
    }
    __syncthreads();
    if(t==0) ctrl[0] = fmaxf(fmaxf(mred[0],mred[1]), fmaxf(mred[2],mred[3]));
    __syncthreads();
    float M = ctrl[0];
    if(M <= EPSC || n >= MAXIT) break;
    u = u_new; r_old = r; n++;
    if(t < 64) vsh[t] = (float)NQ / (tq[0][t]+tq[1][t]+tq[2][t]+tq[3][t]);
    __syncthreads();
  }
  // final plan colsums -> masksum
#pragma unroll
  for(int h=0;h<2;h++){
#pragma unroll
    for(int jj=0;jj<32;jj++) tmat[t][jj] = kr[32*h+jj]*u;
    __syncthreads();
    {
      int j = t & 31, q = t >> 5;
      float ps = 0.f;
#pragma unroll
      for(int rr=0;rr<32;rr++) ps += tmat[q*32+rr][j];
      tq[q][j] = ps;
    }
    __syncthreads();
    if(t < 32) tcol[32*h + t] = tq[0][t]+tq[1][t]+tq[2][t]+tq[3][t]+tq[4][t]+tq[5][t]+tq[6][t]+tq[7][t];
    __syncthreads();
  }
  if(t < 64) atomicAdd(&masksum[t], tcol[t]*vsh[t]);
  // store plan transposed (pitch NUP); inactive threads zero the pad cols
  if(active){
#pragma unroll
    for(int j=0;j<64;j++){
      float val = kr[j]*u*vsh[j];
      ushort h = f2bf(val);
      MThi[(size_t)j*NUP + iu] = h;
      MTlo[(size_t)j*NUP + iu] = f2bf(val - bf2f(h));
    }
  } else {
#pragma unroll
    for(int j=0;j<64;j++){
      MThi[(size_t)j*NUP + iu] = 0;
      MTlo[(size_t)j*NUP + iu] = 0;
    }
  }
  if(b==0 && t<64) vprev[t] = vsh[t];
}

// ---------------- K8: emus via MFMA, hi-only, depth-2 prefetch ----------------
// grid (96 c-tiles of 16, 8 i-segments of 1568), 64 threads (one wave), no LDS
__global__ __launch_bounds__(64) void k_emus(const ushort* __restrict__ MThi, const ushort* __restrict__ ZThi,
                                             float* __restrict__ part){
  int t = threadIdx.x, l15 = t&15, quad = t>>4;
  int cx = blockIdx.x, iy = blockIdx.y;
  int start = iy*1568;
  const ushort* ap[4];
#pragma unroll
  for(int q=0;q<4;q++) ap[q] = MThi + (size_t)(16*q + l15)*NUP + start + quad*8;
  const ushort* bp = ZThi + (size_t)(cx*16 + l15)*NUP + start + quad*8;
  f32x4 acc[4];
#pragma unroll
  for(int q=0;q<4;q++) acc[q] = (f32x4){0.f,0.f,0.f,0.f};
  short8 ab[3][4], bb[3];
#pragma unroll
  for(int s=0;s<2;s++){
#pragma unroll
    for(int q=0;q<4;q++) ab[s][q] = *(const short8*)(ap[q] + s*32);
    bb[s] = *(const short8*)(bp + s*32);
  }
#pragma unroll
  for(int kt=0; kt<49; kt++){
    int cur = kt%3, nx = (kt+2)%3;
    if(kt+2 < 49){
#pragma unroll
      for(int q=0;q<4;q++) ab[nx][q] = *(const short8*)(ap[q] + (kt+2)*32);
      bb[nx] = *(const short8*)(bp + (kt+2)*32);
    }
#pragma unroll
    for(int q=0;q<4;q++)
      acc[q] = __builtin_amdgcn_mfma_f32_16x16x32_bf16(ab[cur][q], bb[cur], acc[q], 0,0,0);
  }
  float* dst = part + (size_t)iy*(NW*DIM);
#pragma unroll
  for(int q=0;q<4;q++)
#pragma unroll
    for(int rg=0;rg<4;rg++)
      dst[(size_t)(16*q + quad*4 + rg)*DIM + cx*16 + l15] = acc[q][rg];
}

// ---------------- K9: mus update (sums 8 partials + labeled const) ----------------
__global__ void k_mus_update(float* __restrict__ mus, const float* __restrict__ emus_lab,
                             const float* __restrict__ part, const float* __restrict__ masksum){
  int idx = blockIdx.x*256 + threadIdx.x;
  int w = idx / DIM;
  float e = emus_lab[idx];
#pragma unroll
  for(int s=0;s<8;s++) e += part[(size_t)s*(NW*DIM) + idx];
  e /= masksum[w];
  mus[idx] += ALPHA * (e - mus[idx]);
}

// ---------------- K10a: labeled onehot rows ----------------
__global__ void k_out_lab(const int* __restrict__ labels, float* __restrict__ out){
  int idx = blockIdx.x*256 + threadIdx.x;
  if(idx < NL*NW){
    int i = idx >> 6, w = idx & 63;
    out[idx] = (labels[i]==w) ? 1.0f : 0.0f;
  }
}

// ---------------- K10b: unlabeled rows: out = log(plan) ----------------
__global__ __launch_bounds__(256) void k_out_u(const ushort* __restrict__ MThi, const ushort* __restrict__ MTlo,
                                               float* __restrict__ out){
  __shared__ float P[64][68];
  int b = blockIdx.x;
  int iu0 = b*64;
  int t = threadIdx.x;
  int w = t>>2, ch = (t&3)*16;
  const ushort* ph = MThi + (size_t)w*NUP + iu0 + ch;
  const ushort* pl = MTlo + (size_t)w*NUP + iu0 + ch;
  short8 h0 = *(const short8*)ph, h1 = *(const short8*)(ph+8);
  short8 l0 = *(const short8*)pl, l1 = *(const short8*)(pl+8);
#pragma unroll
  for(int k=0;k<8;k++){
    P[ch+k][w]   = logf(bf2f((ushort)h0[k]) + bf2f((ushort)l0[k]));
    P[ch+8+k][w] = logf(bf2f((ushort)h1[k]) + bf2f((ushort)l1[k]));
  }
  __syncthreads();
  int r = t>>2, c0 = (t&3)*16;
  float4* dst = (float4*)(out + (size_t)(NL + iu0 + r)*NW + c0);
#pragma unroll
  for(int g=0;g<4;g++) dst[g] = *(float4*)&P[r][c0+4*g];
}

// ---------------- K11: accuracy ----------------
__global__ void k_acc(const ushort* __restrict__ MThi, const ushort* __restrict__ MTlo,
                      const int* __restrict__ labels, float* matchcount){
  int iu = blockIdx.x*256 + threadIdx.x;
  float m = 0.f;
  if(iu < NU){
    float best = -1.f; int bj = 0;
#pragma unroll 8
    for(int w=0;w<64;w++){
      float v = bf2f(MThi[(size_t)w*NUP + iu]) + bf2f(MTlo[(size_t)w*NUP + iu]);
      if(v > best){ best = v; bj = w; }
    }
    m = (labels[NL+iu] == bj) ? 1.f : 0.f;
  }
  float ws = wave_sum(m);
  __shared__ float red[4];
  if((threadIdx.x&63)==0) red[threadIdx.x>>6]=ws;
  __syncthreads();
  if(threadIdx.x==0) atomicAdd(matchcount, red[0]+red[1]+red[2]+red[3]);
}

// ---------------- K12 ----------------
__global__ void k_fin(const float* matchcount, float* __restrict__ out){
  out[(size_t)NTOT*NW]     = (*matchcount) * (1.0f/(float)NU);
  out[(size_t)NTOT*NW + 1] = 0.0f;
}

// ---------------- launch ----------------
extern "C" void kernel_launch(void* const* d_in, const int* in_sizes, int n_in,
                              void* d_out, int out_size, void* d_ws, size_t ws_size,
                              hipStream_t stream){
  const float* X = (const float*)d_in[0];
  const int* labels = (const int*)d_in[1];
  float* out = (float*)d_out;
  float* ws = (float*)d_ws;

  // ws layout (float offsets), total 21,371,976 fl = 85.49 MB (< proven-safe 85.94 MB)
  float*  matchcount = ws + 0;
  float*  munorm     = ws + 4;
  float*  masksum    = ws + 68;
  float*  vprev      = ws + 132;
  float*  csum_l     = ws + 196;
  float*  csum_u     = ws + 1732;
  int*    stamps     = (int*)(ws + 3268);        // 64 ints
  float*  partials   = ws + 3332;                // 6468 -> 9800
  float*  Slc        = ws + 9800;                // 1536 -> 11336
  float*  mus        = ws + 11336;               // 98304 -> 109640
  float*  emus_lab   = ws + 109640;              // 98304 -> 207944
  ushort* mbh        = (ushort*)(ws + 207944);   // 98304 us = 49152 fl -> 257096
  ushort* mbl        = (ushort*)(ws + 257096);   // -> 306248
  float*  Kmat       = ws + 306248;              // 798720 fl -> 1104968
  float*  part       = ws + 306248;              // ALIAS (Kmat dead when k_emus runs): 786432 fl -> 1092680
  ushort* MThi       = (ushort*)(ws + 1104968);  // 64*12544 us = 401408 fl -> 1506376
  ushort* MTlo       = (ushort*)(ws + 1506376);  // -> 1907784
  ushort* Zhi        = (ushort*)(ws + 1907784);  // 12800*1536 us = 9830400 fl -> 11738184
  ushort* ZThi       = (ushort*)(ws + 11738184); // 1536*12544 us = 9633792 fl -> 21371976
  if(ws_size < (size_t)21371976*4) return;

  hipMemsetAsync(ws, 0, 3332*sizeof(float), stream);

  k_prep<<<3200,256,0,stream>>>(X, Zhi);
  k_colsum<<<dim3(3,100),256,0,stream>>>(Zhi, csum_l, csum_u);
  k_finalize_means<<<12,256,0,stream>>>(csum_l, csum_u);
  k_center<<<3200,256,0,stream>>>(Zhi, csum_l, csum_u);
  k_ztrans<<<dim3(195,24),256,0,stream>>>(Zhi, ZThi);
  k_ztpad<<<384,256,0,stream>>>(ZThi);
  k_mus_init<<<64,256,0,stream>>>(Zhi, mus);
  k_vinit<<<1,64,0,stream>>>(vprev);
  k_slc<<<6,256,0,stream>>>(mus, Slc);
  k_elab<<<384,256,0,stream>>>(mus, Slc, emus_lab);

  for(int e=0; e<=EPOCHS; e++){
    k_epoch_prep<<<64,256,0,stream>>>(mus, munorm, masksum, matchcount, stamps, mbh, mbl);
    k_dist<<<780,64,0,stream>>>(mbh, mbl, Zhi, munorm, Kmat);
    k_sinkhorn<<<SB_NB,256,0,stream>>>(Kmat, MThi, MTlo, partials, stamps, vprev, masksum);
    if(e < EPOCHS){
      k_emus<<<dim3(96,8),64,0,stream>>>(MThi, ZThi, part);
      k_mus_update<<<384,256,0,stream>>>(mus, emus_lab, part, masksum);
    }
  }
  k_out_lab<<<80,256,0,stream>>>(labels, out);
  k_out_u<<<195,256,0,stream>>>(MThi, MTlo, out);
  k_acc<<<49,256,0,stream>>>(MThi, MTlo, labels, matchcount);
  k_fin<<<1,1,0,stream>>>(matchcount, out);
}

// Round 5
// 2719.639 us; speedup vs baseline: 1.7092x; 1.0010x over previous
//
#include <hip/hip_runtime.h>
#include <math.h>

#define NW 64
#define NS 5
#define NQ 195
#define DIM 1536
#define NTOT 12800
#define NL 320
#define NU 12480
#define NUP 12544
#define ALPHA 0.2f
#define EPOCHS 20
#define EPSC 1e-6f
#define MAXIT 1000
#define SB_NB 49

typedef float f32x4 __attribute__((ext_vector_type(4)));
typedef short short8 __attribute__((ext_vector_type(8)));

// ---------------- helpers ----------------
__device__ inline float wave_sum(float x){
#pragma unroll
  for(int o=32;o;o>>=1) x += __shfl_xor(x,o);
  return x;
}
__device__ inline float bf2f(ushort h){
  union{uint u; float f;} c; c.u = ((uint)h)<<16; return c.f;
}
__device__ inline ushort f2bf(float x){
  union{float f; uint u;} c; c.f = x;
  uint r = c.u + 0x7FFFu + ((c.u>>16)&1u);
  return (ushort)(r>>16);
}

// ---------------- K1: sqrt power transform + row l2norm -> Zhi bf16 ----------------
__global__ __launch_bounds__(256) void k_prep(const float* __restrict__ X, ushort* __restrict__ Zhi){
  int row = blockIdx.x*4 + (threadIdx.x>>6);
  int lane = threadIdx.x & 63;
  const float4* xp = (const float4*)(X + (size_t)row*DIM);
  float4 v[6]; float ss = 0.f;
#pragma unroll
  for(int q=0;q<6;q++){
    float4 t = xp[lane + 64*q];
    t.x = sqrtf(t.x+1e-6f); t.y = sqrtf(t.y+1e-6f); t.z = sqrtf(t.z+1e-6f); t.w = sqrtf(t.w+1e-6f);
    v[q]=t; ss += t.x*t.x+t.y*t.y+t.z*t.z+t.w*t.w;
  }
  ss = wave_sum(ss);
  float inv = 1.f / fmaxf(sqrtf(ss), 1e-12f);
#pragma unroll
  for(int q=0;q<6;q++){
    float4 t = v[q];
    ushort4 h;
    h.x=f2bf(t.x*inv); h.y=f2bf(t.y*inv); h.z=f2bf(t.z*inv); h.w=f2bf(t.w*inv);
    *(ushort4*)&Zhi[(size_t)row*DIM + 4*lane + 256*q] = h;
  }
}

// ---------------- K2a: segment column sums ----------------
__global__ __launch_bounds__(256) void k_colsum(const ushort* __restrict__ Zhi,
                                                float* __restrict__ csum_l, float* __restrict__ csum_u){
  int c0 = blockIdx.x*512 + 2*threadIdx.x;
  int r0 = blockIdx.y*128;
  float al0=0.f, al1=0.f, au0=0.f, au1=0.f;
  for(int r=r0; r<r0+128; r++){
    ushort2 h = *(const ushort2*)&Zhi[(size_t)r*DIM + c0];
    float x0 = bf2f(h.x), x1 = bf2f(h.y);
    if(r < NL){ al0+=x0; al1+=x1; } else { au0+=x0; au1+=x1; }
  }
  if(r0 < NL){ atomicAdd(&csum_l[c0], al0); atomicAdd(&csum_l[c0+1], al1); }
  if(r0+128 > NL){ atomicAdd(&csum_u[c0], au0); atomicAdd(&csum_u[c0+1], au1); }
}

// ---------------- K2b ----------------
__global__ void k_finalize_means(float* csum_l, float* csum_u){
  int idx = blockIdx.x*256 + threadIdx.x;
  if(idx < DIM) csum_l[idx] *= (1.0f/NL);
  else if(idx < 2*DIM) csum_u[idx-DIM] *= (1.0f/NU);
}

// ---------------- K3: center + row l2norm (in place) ----------------
__global__ __launch_bounds__(256) void k_center(ushort* __restrict__ Zhi,
                                                const float* __restrict__ cm_l, const float* __restrict__ cm_u){
  int row = blockIdx.x*4 + (threadIdx.x>>6);
  int lane = threadIdx.x & 63;
  const float4* cp = (const float4*)((row < NL) ? cm_l : cm_u);
  float4 v[6]; float ss = 0.f;
#pragma unroll
  for(int q=0;q<6;q++){
    ushort4 h = *(const ushort4*)&Zhi[(size_t)row*DIM + 4*lane + 256*q];
    float4 m = cp[lane + 64*q];
    float4 t;
    t.x = bf2f(h.x) - m.x; t.y = bf2f(h.y) - m.y;
    t.z = bf2f(h.z) - m.z; t.w = bf2f(h.w) - m.w;
    v[q]=t; ss += t.x*t.x+t.y*t.y+t.z*t.z+t.w*t.w;
  }
  ss = wave_sum(ss);
  float inv = 1.f / fmaxf(sqrtf(ss), 1e-12f);
#pragma unroll
  for(int q=0;q<6;q++){
    float4 t = v[q];
    ushort4 h;
    h.x=f2bf(t.x*inv); h.y=f2bf(t.y*inv); h.z=f2bf(t.z*inv); h.w=f2bf(t.w*inv);
    *(ushort4*)&Zhi[(size_t)row*DIM + 4*lane + 256*q] = h;
  }
}

// ---------------- K3b: tile-transpose unlabeled Z -> ZT[c][iu] (pitch NUP) ----------------
__global__ __launch_bounds__(256) void k_ztrans(const ushort* __restrict__ Zhi, ushort* __restrict__ ZT){
  __shared__ ushort T[64][66];
  int ti = blockIdx.x, tc = blockIdx.y;
  int t = threadIdx.x;
  int r = t>>2, ch = (t&3)*16;
  const ushort* src = Zhi + (size_t)(NL + ti*64 + r)*DIM + tc*64 + ch;
  short8 a = *(const short8*)src;
  short8 b = *(const short8*)(src+8);
#pragma unroll
  for(int k=0;k<8;k++){ T[r][ch+k] = (ushort)a[k]; T[r][ch+8+k] = (ushort)b[k]; }
  __syncthreads();
  short8 o0, o1;
#pragma unroll
  for(int k=0;k<8;k++){ o0[k] = (short)T[ch+k][r]; o1[k] = (short)T[ch+8+k][r]; }
  ushort* dst = ZT + (size_t)(tc*64 + r)*NUP + ti*64 + ch;
  *(short8*)dst = o0;
  *(short8*)(dst+8) = o1;
}

// ---------------- K3c: zero ZT pad cols [NU, NUP) ----------------
__global__ void k_ztpad(ushort* __restrict__ ZT){
  int idx = blockIdx.x*256 + threadIdx.x;   // < 1536*64
  int c = idx >> 6, j = idx & 63;
  if(c < DIM) ZT[(size_t)c*NUP + NU + j] = 0;
}

// ---------------- K4: init mus from labeled shots ----------------
__global__ void k_mus_init(const ushort* __restrict__ Zhi, float* __restrict__ mus){
  int w = blockIdx.x;
#pragma unroll
  for(int q=0;q<6;q++){
    int c = threadIdx.x + 256*q;
    float s = 0.f;
#pragma unroll
    for(int sh=0; sh<NS; sh++) s += bf2f(Zhi[(size_t)(sh*NW + w)*DIM + c]);
    mus[(size_t)w*DIM + c] = s * 0.2f;
  }
}

// ---------------- K4b: vprev = 1 ----------------
__global__ void k_vinit(float* __restrict__ vprev){
  if(threadIdx.x < 64) vprev[threadIdx.x] = 1.0f;
}

// ---------------- K4c: S[c] = 5 * sum_w mus0[w][c] ----------------
__global__ void k_slc(const float* __restrict__ mus, float* __restrict__ S){
  int c = blockIdx.x*256 + threadIdx.x;
  float s = 0.f;
  for(int w=0;w<64;w++) s += mus[(size_t)w*DIM + c];
  S[c] = 5.0f * s;
}

// ---------------- K4d: emus_lab = S[c] + (e-1)*5*mus0 ----------------
__global__ void k_elab(const float* __restrict__ mus, const float* __restrict__ S,
                       float* __restrict__ emus_lab){
  int idx = blockIdx.x*256 + threadIdx.x;
  int c = idx % DIM;
  emus_lab[idx] = S[c] + (expf(1.0f)-1.0f)*5.0f*mus[idx];
}

// ---------------- K5: per-epoch prep: munorm, masksum, stamps, mus->bf16 hi/lo ----------------
__global__ void k_epoch_prep(const float* __restrict__ mus, float* munorm, float* masksum,
                             float* matchcount, int* stamps,
                             ushort* __restrict__ mbh, ushort* __restrict__ mbl){
  int w = blockIdx.x;
  float ss = 0.f;
#pragma unroll
  for(int q=0;q<6;q++){
    int c = threadIdx.x + 256*q;
    float v = mus[(size_t)w*DIM + c];
    ss += v*v;
    ushort h = f2bf(v);
    mbh[(size_t)w*DIM + c] = h;
    mbl[(size_t)w*DIM + c] = f2bf(v - bf2f(h));
  }
  __shared__ float red[4];
  float wsu = wave_sum(ss);
  if((threadIdx.x&63)==0) red[threadIdx.x>>6]=wsu;
  __syncthreads();
  if(threadIdx.x==0){
    munorm[w] = red[0]+red[1]+red[2]+red[3];
    masksum[w] = 315.0f + 5.0f*expf(1.0f);
    if(w==0) *matchcount = 0.f;
    if(w < SB_NB) stamps[w] = 0;
  }
}

// ---------------- K6: dist partial GEMM via MFMA, split-K=3 -> raw dot partials ----------------
// grid (780, 3) x 64: wave = 16 samples x 64 ways over k-chunk of 512 (16 steps of 32)
__global__ __launch_bounds__(64,1) void k_dist(const ushort* __restrict__ mbh, const ushort* __restrict__ mbl,
                                               const ushort* __restrict__ Zhi,
                                               float* __restrict__ Dp0, float* __restrict__ Dp1,
                                               float* __restrict__ Dp2){
  int t = threadIdx.x, l15 = t&15, quad = t>>4;
  int b = blockIdx.x, kc = blockIdx.y;
  int kbase = kc*512;
  const ushort* ap = Zhi + (size_t)(NL + b*16 + l15)*DIM + kbase + quad*8;
  const ushort* bhp[4]; const ushort* blp[4];
#pragma unroll
  for(int q=0;q<4;q++){
    bhp[q] = mbh + (size_t)(16*q + l15)*DIM + kbase + quad*8;
    blp[q] = mbl + (size_t)(16*q + l15)*DIM + kbase + quad*8;
  }
  f32x4 acc[4];
#pragma unroll
  for(int q=0;q<4;q++) acc[q] = (f32x4){0.f,0.f,0.f,0.f};
  short8 abuf[3], hbuf[3][4], lbuf[3][4];
#pragma unroll
  for(int s=0;s<2;s++){
    abuf[s] = *(const short8*)(ap + s*32);
#pragma unroll
    for(int q=0;q<4;q++){
      hbuf[s][q] = *(const short8*)(bhp[q] + s*32);
      lbuf[s][q] = *(const short8*)(blp[q] + s*32);
    }
  }
#pragma unroll
  for(int kt=0; kt<16; kt++){
    int cur = kt%3, nx = (kt+2)%3;
    if(kt+2 < 16){
      abuf[nx] = *(const short8*)(ap + (kt+2)*32);
#pragma unroll
      for(int q=0;q<4;q++){
        hbuf[nx][q] = *(const short8*)(bhp[q] + (kt+2)*32);
        lbuf[nx][q] = *(const short8*)(blp[q] + (kt+2)*32);
      }
    }
#pragma unroll
    for(int q=0;q<4;q++){
      acc[q] = __builtin_amdgcn_mfma_f32_16x16x32_bf16(abuf[cur], hbuf[cur][q], acc[q], 0,0,0);
      acc[q] = __builtin_amdgcn_mfma_f32_16x16x32_bf16(abuf[cur], lbuf[cur][q], acc[q], 0,0,0);
    }
  }
  float* D = (kc==0) ? Dp0 : ((kc==1) ? Dp1 : Dp2);
  int samp0 = b*16 + quad*4;
#pragma unroll
  for(int q=0;q<4;q++){
    int w = 16*q + l15;
#pragma unroll
    for(int rg=0;rg<4;rg++)
      D[(size_t)(samp0+rg)*NW + w] = acc[q][rg];
  }
}

// ---------------- K7: persistent Sinkhorn (partials -> exp epilogue on load) ----------------
__global__ __launch_bounds__(256,1) void k_sinkhorn(const float* __restrict__ Dp0, const float* __restrict__ Dp1,
                                                    const float* __restrict__ Dp2, const float* __restrict__ munorm,
                                                    ushort* __restrict__ MThi, ushort* __restrict__ MTlo,
                                                    float* __restrict__ partials, int* __restrict__ stamps,
                                                    float* __restrict__ vprev, float* __restrict__ masksum){
  __shared__ __align__(16) float vsh[64];
  __shared__ float mnsh[64];
  __shared__ float tmat[256][33];
  __shared__ float tq[8][64];
  __shared__ float tcol[64];
  __shared__ float mred[4];
  __shared__ float ctrl[1];
  int t = threadIdx.x, b = blockIdx.x;
  int iu = b*256 + t;
  bool active = iu < NU;
  if(t < 64){ vsh[t] = vprev[t]; mnsh[t] = munorm[t]; }
  __syncthreads();
  float kr[64];
  if(active){
    const float4* p0 = (const float4*)(Dp0 + (size_t)iu*NW);
    const float4* p1 = (const float4*)(Dp1 + (size_t)iu*NW);
    const float4* p2 = (const float4*)(Dp2 + (size_t)iu*NW);
#pragma unroll
    for(int q=0;q<16;q++){
      float4 a = p0[q], c = p1[q], d = p2[q];
      float sv[4] = {a.x+c.x+d.x, a.y+c.y+d.y, a.z+c.z+d.z, a.w+c.w+d.w};
#pragma unroll
      for(int i=0;i<4;i++){
        float d2 = 1.0f + mnsh[4*q+i] - 2.0f*sv[i];
        kr[4*q+i] = expf(-10.0f * sqrtf(fmaxf(d2, 0.0f)));
      }
    }
  } else {
#pragma unroll
    for(int j=0;j<64;j++) kr[j]=0.f;
  }
  float u = 1.0f, r_old = 0.0f;
  int n = 0;
  while(true){
    float s = 0.f;
#pragma unroll
    for(int q=0;q<16;q++){
      float4 vv = *(const float4*)&vsh[4*q];
      s += kr[4*q]*vv.x + kr[4*q+1]*vv.y + kr[4*q+2]*vv.z + kr[4*q+3]*vv.w;
    }
    float r = u * s;
    float diff = fabsf(r - r_old);
    float u_new = (active && s > 0.f) ? 1.0f/s : 0.0f;
    {
      float wmx = diff;
#pragma unroll
      for(int o=32;o;o>>=1) wmx = fmaxf(wmx, __shfl_xor(wmx,o));
      if((t&63)==0) mred[t>>6] = wmx;
    }
#pragma unroll
    for(int h=0;h<2;h++){
#pragma unroll
      for(int jj=0;jj<32;jj++) tmat[t][jj] = kr[32*h+jj]*u_new;
      __syncthreads();
      {
        int j = t & 31, q = t >> 5;
        float ps = 0.f;
#pragma unroll
        for(int rr=0;rr<32;rr++) ps += tmat[q*32+rr][j];
        tq[q][j] = ps;
      }
      __syncthreads();
      if(t < 32) tcol[32*h + t] = tq[0][t]+tq[1][t]+tq[2][t]+tq[3][t]+tq[4][t]+tq[5][t]+tq[6][t]+tq[7][t];
      __syncthreads();
    }
    int buf = n & 1;
    float* P = partials + buf*(SB_NB*66) + b*66;
    if(t < 64){
      __hip_atomic_store(&P[t], tcol[t], __ATOMIC_RELAXED, __HIP_MEMORY_SCOPE_AGENT);
    } else if(t == 64){
      float bm = fmaxf(fmaxf(mred[0],mred[1]), fmaxf(mred[2],mred[3]));
      __hip_atomic_store(&P[64], bm, __ATOMIC_RELAXED, __HIP_MEMORY_SCOPE_AGENT);
    }
    __syncthreads();
    if(t == 0){
      __threadfence();
      __hip_atomic_store(&stamps[b], n+1, __ATOMIC_RELEASE, __HIP_MEMORY_SCOPE_AGENT);
    }
    if(t < SB_NB){
      while(__hip_atomic_load(&stamps[t], __ATOMIC_ACQUIRE, __HIP_MEMORY_SCOPE_AGENT) <= n){}
    }
    __syncthreads();
    {
      int j = t & 63, q4 = t >> 6;
      float ps = 0.f, pm = 0.f;
      const float* PB = partials + buf*(SB_NB*66);
      for(int bb=q4; bb<SB_NB; bb+=4){
        ps += __hip_atomic_load(&PB[bb*66 + j], __ATOMIC_RELAXED, __HIP_MEMORY_SCOPE_AGENT);
        if(j==0) pm = fmaxf(pm, __hip_atomic_load(&PB[bb*66 + 64], __ATOMIC_RELAXED, __HIP_MEMORY_SCOPE_AGENT));
      }
      tq[q4][j] = ps;
      if(j==0) mred[q4] = pm;
    }
    __syncthreads();
    if(t==0) ctrl[0] = fmaxf(fmaxf(mred[0],mred[1]), fmaxf(mred[2],mred[3]));
    __syncthreads();
    float M = ctrl[0];
    if(M <= EPSC || n >= MAXIT) break;
    u = u_new; r_old = r; n++;
    if(t < 64) vsh[t] = (float)NQ / (tq[0][t]+tq[1][t]+tq[2][t]+tq[3][t]);
    __syncthreads();
  }
  // final plan colsums -> masksum
#pragma unroll
  for(int h=0;h<2;h++){
#pragma unroll
    for(int jj=0;jj<32;jj++) tmat[t][jj] = kr[32*h+jj]*u;
    __syncthreads();
    {
      int j = t & 31, q = t >> 5;
      float ps = 0.f;
#pragma unroll
      for(int rr=0;rr<32;rr++) ps += tmat[q*32+rr][j];
      tq[q][j] = ps;
    }
    __syncthreads();
    if(t < 32) tcol[32*h + t] = tq[0][t]+tq[1][t]+tq[2][t]+tq[3][t]+tq[4][t]+tq[5][t]+tq[6][t]+tq[7][t];
    __syncthreads();
  }
  if(t < 64) atomicAdd(&masksum[t], tcol[t]*vsh[t]);
  // store plan transposed (pitch NUP); safe to overlay Dp: all blocks' Dp reads completed
  // before their first stamp (release waits loads), and exit requires all stamps >= 1.
  if(active){
#pragma unroll
    for(int j=0;j<64;j++){
      float val = kr[j]*u*vsh[j];
      ushort h = f2bf(val);
      MThi[(size_t)j*NUP + iu] = h;
      MTlo[(size_t)j*NUP + iu] = f2bf(val - bf2f(h));
    }
  } else {
#pragma unroll
    for(int j=0;j<64;j++){
      MThi[(size_t)j*NUP + iu] = 0;
      MTlo[(size_t)j*NUP + iu] = 0;
    }
  }
  if(b==0 && t<64) vprev[t] = vsh[t];
}

// ---------------- K8: emus via MFMA, hi-only, depth-2 prefetch ----------------
__global__ __launch_bounds__(64) void k_emus(const ushort* __restrict__ MThi, const ushort* __restrict__ ZThi,
                                             float* __restrict__ part){
  int t = threadIdx.x, l15 = t&15, quad = t>>4;
  int cx = blockIdx.x, iy = blockIdx.y;
  int start = iy*1568;
  const ushort* ap[4];
#pragma unroll
  for(int q=0;q<4;q++) ap[q] = MThi + (size_t)(16*q + l15)*NUP + start + quad*8;
  const ushort* bp = ZThi + (size_t)(cx*16 + l15)*NUP + start + quad*8;
  f32x4 acc[4];
#pragma unroll
  for(int q=0;q<4;q++) acc[q] = (f32x4){0.f,0.f,0.f,0.f};
  short8 ab[3][4], bb[3];
#pragma unroll
  for(int s=0;s<2;s++){
#pragma unroll
    for(int q=0;q<4;q++) ab[s][q] = *(const short8*)(ap[q] + s*32);
    bb[s] = *(const short8*)(bp + s*32);
  }
#pragma unroll
  for(int kt=0; kt<49; kt++){
    int cur = kt%3, nx = (kt+2)%3;
    if(kt+2 < 49){
#pragma unroll
      for(int q=0;q<4;q++) ab[nx][q] = *(const short8*)(ap[q] + (kt+2)*32);
      bb[nx] = *(const short8*)(bp + (kt+2)*32);
    }
#pragma unroll
    for(int q=0;q<4;q++)
      acc[q] = __builtin_amdgcn_mfma_f32_16x16x32_bf16(ab[cur][q], bb[cur], acc[q], 0,0,0);
  }
  float* dst = part + (size_t)iy*(NW*DIM);
#pragma unroll
  for(int q=0;q<4;q++)
#pragma unroll
    for(int rg=0;rg<4;rg++)
      dst[(size_t)(16*q + quad*4 + rg)*DIM + cx*16 + l15] = acc[q][rg];
}

// ---------------- K9: mus update (sums 8 partials + labeled const) ----------------
__global__ void k_mus_update(float* __restrict__ mus, const float* __restrict__ emus_lab,
                             const float* __restrict__ part, const float* __restrict__ masksum){
  int idx = blockIdx.x*256 + threadIdx.x;
  int w = idx / DIM;
  float e = emus_lab[idx];
#pragma unroll
  for(int s=0;s<8;s++) e += part[(size_t)s*(NW*DIM) + idx];
  e /= masksum[w];
  mus[idx] += ALPHA * (e - mus[idx]);
}

// ---------------- K10a: labeled onehot rows ----------------
__global__ void k_out_lab(const int* __restrict__ labels, float* __restrict__ out){
  int idx = blockIdx.x*256 + threadIdx.x;
  if(idx < NL*NW){
    int i = idx >> 6, w = idx & 63;
    out[idx] = (labels[i]==w) ? 1.0f : 0.0f;
  }
}

// ---------------- K10b: unlabeled rows: out = log(plan) ----------------
__global__ __launch_bounds__(256) void k_out_u(const ushort* __restrict__ MThi, const ushort* __restrict__ MTlo,
                                               float* __restrict__ out){
  __shared__ float P[64][68];
  int b = blockIdx.x;
  int iu0 = b*64;
  int t = threadIdx.x;
  int w = t>>2, ch = (t&3)*16;
  const ushort* ph = MThi + (size_t)w*NUP + iu0 + ch;
  const ushort* pl = MTlo + (size_t)w*NUP + iu0 + ch;
  short8 h0 = *(const short8*)ph, h1 = *(const short8*)(ph+8);
  short8 l0 = *(const short8*)pl, l1 = *(const short8*)(pl+8);
#pragma unroll
  for(int k=0;k<8;k++){
    P[ch+k][w]   = logf(bf2f((ushort)h0[k]) + bf2f((ushort)l0[k]));
    P[ch+8+k][w] = logf(bf2f((ushort)h1[k]) + bf2f((ushort)l1[k]));
  }
  __syncthreads();
  int r = t>>2, c0 = (t&3)*16;
  float4* dst = (float4*)(out + (size_t)(NL + iu0 + r)*NW + c0);
#pragma unroll
  for(int g=0;g<4;g++) dst[g] = *(float4*)&P[r][c0+4*g];
}

// ---------------- K11: accuracy ----------------
__global__ void k_acc(const ushort* __restrict__ MThi, const ushort* __restrict__ MTlo,
                      const int* __restrict__ labels, float* matchcount){
  int iu = blockIdx.x*256 + threadIdx.x;
  float m = 0.f;
  if(iu < NU){
    float best = -1.f; int bj = 0;
#pragma unroll 8
    for(int w=0;w<64;w++){
      float v = bf2f(MThi[(size_t)w*NUP + iu]) + bf2f(MTlo[(size_t)w*NUP + iu]);
      if(v > best){ best = v; bj = w; }
    }
    m = (labels[NL+iu] == bj) ? 1.f : 0.f;
  }
  float ws = wave_sum(m);
  __shared__ float red[4];
  if((threadIdx.x&63)==0) red[threadIdx.x>>6]=ws;
  __syncthreads();
  if(threadIdx.x==0) atomicAdd(matchcount, red[0]+red[1]+red[2]+red[3]);
}

// ---------------- K12 ----------------
__global__ void k_fin(const float* matchcount, float* __restrict__ out){
  out[(size_t)NTOT*NW]     = (*matchcount) * (1.0f/(float)NU);
  out[(size_t)NTOT*NW + 1] = 0.0f;
}

// ---------------- launch ----------------
extern "C" void kernel_launch(void* const* d_in, const int* in_sizes, int n_in,
                              void* d_out, int out_size, void* d_ws, size_t ws_size,
                              hipStream_t stream){
  const float* X = (const float*)d_in[0];
  const int* labels = (const int*)d_in[1];
  float* out = (float*)d_out;
  float* ws = (float*)d_ws;

  // ws layout (float offsets), total 21,367,880 fl = 85.47 MB (< proven-safe 85.94 MB)
  float*  matchcount = ws + 0;
  float*  munorm     = ws + 4;
  float*  masksum    = ws + 68;
  float*  vprev      = ws + 132;
  float*  csum_l     = ws + 196;
  float*  csum_u     = ws + 1732;
  int*    stamps     = (int*)(ws + 3268);        // 64 ints
  float*  partials   = ws + 3332;                // 6468 -> 9800
  float*  Slc        = ws + 9800;                // 1536 -> 11336
  float*  mus        = ws + 11336;               // 98304 -> 109640
  float*  emus_lab   = ws + 109640;              // 98304 -> 207944
  ushort* mbh        = (ushort*)(ws + 207944);   // 49152 fl -> 257096
  ushort* mbl        = (ushort*)(ws + 257096);   // -> 306248
  // union region U: 1,597,440 fl -> 1,903,688
  //   Dp0  = U[0..798,720)        (dist partial chunk 0)
  //   Dp1  = U[798,720..1,597,440) (chunk 1); chunk 2 -> d_out scratch
  //   part = U[0..786,432)         (emus partials; lifetime disjoint from Dp)
  //   MThi = U[786,432..1,187,840), MTlo = U[1,187,840..1,589,248)
  //   (MT overlay safe: every block's Dp reads complete before its first release-stamp,
  //    and no block exits the sinkhorn loop before all blocks stamp >= 1)
  float*  U          = ws + 306248;
  float*  Dp0        = U;
  float*  Dp1        = U + 798720;
  float*  part       = U;
  ushort* MThi       = (ushort*)(U + 786432);
  ushort* MTlo       = (ushort*)(U + 1187840);
  ushort* Zhi        = (ushort*)(ws + 1903688);  // 9,830,400 fl -> 11,734,088
  ushort* ZThi       = (ushort*)(ws + 11734088); // 9,633,792 fl -> 21,367,880
  float*  Dp2        = out;                      // d_out scratch (798,720 <= 819,200), rewritten by k_out
  if(ws_size < (size_t)21367880*4) return;

  hipMemsetAsync(ws, 0, 3332*sizeof(float), stream);

  k_prep<<<3200,256,0,stream>>>(X, Zhi);
  k_colsum<<<dim3(3,100),256,0,stream>>>(Zhi, csum_l, csum_u);
  k_finalize_means<<<12,256,0,stream>>>(csum_l, csum_u);
  k_center<<<3200,256,0,stream>>>(Zhi, csum_l, csum_u);
  k_ztrans<<<dim3(195,24),256,0,stream>>>(Zhi, ZThi);
  k_ztpad<<<384,256,0,stream>>>(ZThi);
  k_mus_init<<<64,256,0,stream>>>(Zhi, mus);
  k_vinit<<<1,64,0,stream>>>(vprev);
  k_slc<<<6,256,0,stream>>>(mus, Slc);
  k_elab<<<384,256,0,stream>>>(mus, Slc, emus_lab);

  for(int e=0; e<=EPOCHS; e++){
    k_epoch_prep<<<64,256,0,stream>>>(mus, munorm, masksum, matchcount, stamps, mbh, mbl);
    k_dist<<<dim3(780,3),64,0,stream>>>(mbh, mbl, Zhi, Dp0, Dp1, Dp2);
    k_sinkhorn<<<SB_NB,256,0,stream>>>(Dp0, Dp1, Dp2, munorm, MThi, MTlo, partials, stamps, vprev, masksum);
    if(e < EPOCHS){
      k_emus<<<dim3(96,8),64,0,stream>>>(MThi, ZThi, part);
      k_mus_update<<<384,256,0,stream>>>(mus, emus_lab, part, masksum);
    }
  }
  k_out_lab<<<80,256,0,stream>>>(labels, out);
  k_out_u<<<195,256,0,stream>>>(MThi, MTlo, out);
  k_acc<<<49,256,0,stream>>>(MThi, MTlo, labels, matchcount);
  k_fin<<<1,1,0,stream>>>(matchcount, out);
}

// Round 6
// 2648.964 us; speedup vs baseline: 1.7548x; 1.0267x over previous
//
#include <hip/hip_runtime.h>
#include <math.h>

#define NW 64
#define NS 5
#define NQ 195
#define DIM 1536
#define NTOT 12800
#define NL 320
#define NU 12480
#define NUP 12544
#define ALPHA 0.2f
#define EPOCHS 20
#define EPSC 1e-6f
#define MAXIT 1000
#define SB_NB 49

typedef float f32x4 __attribute__((ext_vector_type(4)));
typedef short short8 __attribute__((ext_vector_type(8)));

// ---------------- helpers ----------------
__device__ inline float wave_sum(float x){
#pragma unroll
  for(int o=32;o;o>>=1) x += __shfl_xor(x,o);
  return x;
}
__device__ inline float bf2f(ushort h){
  union{uint u; float f;} c; c.u = ((uint)h)<<16; return c.f;
}
__device__ inline ushort f2bf(float x){
  union{float f; uint u;} c; c.f = x;
  uint r = c.u + 0x7FFFu + ((c.u>>16)&1u);
  return (ushort)(r>>16);
}

// ---------------- K1: sqrt power transform + row l2norm -> Zhi bf16 ----------------
__global__ __launch_bounds__(256) void k_prep(const float* __restrict__ X, ushort* __restrict__ Zhi){
  int row = blockIdx.x*4 + (threadIdx.x>>6);
  int lane = threadIdx.x & 63;
  const float4* xp = (const float4*)(X + (size_t)row*DIM);
  float4 v[6]; float ss = 0.f;
#pragma unroll
  for(int q=0;q<6;q++){
    float4 t = xp[lane + 64*q];
    t.x = sqrtf(t.x+1e-6f); t.y = sqrtf(t.y+1e-6f); t.z = sqrtf(t.z+1e-6f); t.w = sqrtf(t.w+1e-6f);
    v[q]=t; ss += t.x*t.x+t.y*t.y+t.z*t.z+t.w*t.w;
  }
  ss = wave_sum(ss);
  float inv = 1.f / fmaxf(sqrtf(ss), 1e-12f);
#pragma unroll
  for(int q=0;q<6;q++){
    float4 t = v[q];
    ushort4 h;
    h.x=f2bf(t.x*inv); h.y=f2bf(t.y*inv); h.z=f2bf(t.z*inv); h.w=f2bf(t.w*inv);
    *(ushort4*)&Zhi[(size_t)row*DIM + 4*lane + 256*q] = h;
  }
}

// ---------------- K2a: segment column sums ----------------
__global__ __launch_bounds__(256) void k_colsum(const ushort* __restrict__ Zhi,
                                                float* __restrict__ csum_l, float* __restrict__ csum_u){
  int c0 = blockIdx.x*512 + 2*threadIdx.x;
  int r0 = blockIdx.y*128;
  float al0=0.f, al1=0.f, au0=0.f, au1=0.f;
  for(int r=r0; r<r0+128; r++){
    ushort2 h = *(const ushort2*)&Zhi[(size_t)r*DIM + c0];
    float x0 = bf2f(h.x), x1 = bf2f(h.y);
    if(r < NL){ al0+=x0; al1+=x1; } else { au0+=x0; au1+=x1; }
  }
  if(r0 < NL){ atomicAdd(&csum_l[c0], al0); atomicAdd(&csum_l[c0+1], al1); }
  if(r0+128 > NL){ atomicAdd(&csum_u[c0], au0); atomicAdd(&csum_u[c0+1], au1); }
}

// ---------------- K2b ----------------
__global__ void k_finalize_means(float* csum_l, float* csum_u){
  int idx = blockIdx.x*256 + threadIdx.x;
  if(idx < DIM) csum_l[idx] *= (1.0f/NL);
  else if(idx < 2*DIM) csum_u[idx-DIM] *= (1.0f/NU);
}

// ---------------- K3: center + row l2norm (in place) ----------------
__global__ __launch_bounds__(256) void k_center(ushort* __restrict__ Zhi,
                                                const float* __restrict__ cm_l, const float* __restrict__ cm_u){
  int row = blockIdx.x*4 + (threadIdx.x>>6);
  int lane = threadIdx.x & 63;
  const float4* cp = (const float4*)((row < NL) ? cm_l : cm_u);
  float4 v[6]; float ss = 0.f;
#pragma unroll
  for(int q=0;q<6;q++){
    ushort4 h = *(const ushort4*)&Zhi[(size_t)row*DIM + 4*lane + 256*q];
    float4 m = cp[lane + 64*q];
    float4 t;
    t.x = bf2f(h.x) - m.x; t.y = bf2f(h.y) - m.y;
    t.z = bf2f(h.z) - m.z; t.w = bf2f(h.w) - m.w;
    v[q]=t; ss += t.x*t.x+t.y*t.y+t.z*t.z+t.w*t.w;
  }
  ss = wave_sum(ss);
  float inv = 1.f / fmaxf(sqrtf(ss), 1e-12f);
#pragma unroll
  for(int q=0;q<6;q++){
    float4 t = v[q];
    ushort4 h;
    h.x=f2bf(t.x*inv); h.y=f2bf(t.y*inv); h.z=f2bf(t.z*inv); h.w=f2bf(t.w*inv);
    *(ushort4*)&Zhi[(size_t)row*DIM + 4*lane + 256*q] = h;
  }
}

// ---------------- K3b: tile-transpose unlabeled Z -> ZT[c][iu] (pitch NUP) ----------------
__global__ __launch_bounds__(256) void k_ztrans(const ushort* __restrict__ Zhi, ushort* __restrict__ ZT){
  __shared__ ushort T[64][66];
  int ti = blockIdx.x, tc = blockIdx.y;
  int t = threadIdx.x;
  int r = t>>2, ch = (t&3)*16;
  const ushort* src = Zhi + (size_t)(NL + ti*64 + r)*DIM + tc*64 + ch;
  short8 a = *(const short8*)src;
  short8 b = *(const short8*)(src+8);
#pragma unroll
  for(int k=0;k<8;k++){ T[r][ch+k] = (ushort)a[k]; T[r][ch+8+k] = (ushort)b[k]; }
  __syncthreads();
  short8 o0, o1;
#pragma unroll
  for(int k=0;k<8;k++){ o0[k] = (short)T[ch+k][r]; o1[k] = (short)T[ch+8+k][r]; }
  ushort* dst = ZT + (size_t)(tc*64 + r)*NUP + ti*64 + ch;
  *(short8*)dst = o0;
  *(short8*)(dst+8) = o1;
}

// ---------------- K3c: zero ZT pad cols [NU, NUP) ----------------
__global__ void k_ztpad(ushort* __restrict__ ZT){
  int idx = blockIdx.x*256 + threadIdx.x;   // < 1536*64
  int c = idx >> 6, j = idx & 63;
  if(c < DIM) ZT[(size_t)c*NUP + NU + j] = 0;
}

// ---------------- K4: init mus from labeled shots ----------------
__global__ void k_mus_init(const ushort* __restrict__ Zhi, float* __restrict__ mus){
  int w = blockIdx.x;
#pragma unroll
  for(int q=0;q<6;q++){
    int c = threadIdx.x + 256*q;
    float s = 0.f;
#pragma unroll
    for(int sh=0; sh<NS; sh++) s += bf2f(Zhi[(size_t)(sh*NW + w)*DIM + c]);
    mus[(size_t)w*DIM + c] = s * 0.2f;
  }
}

// ---------------- K4b: vprev = 1 ----------------
__global__ void k_vinit(float* __restrict__ vprev){
  if(threadIdx.x < 64) vprev[threadIdx.x] = 1.0f;
}

// ---------------- K4c: S[c] = 5 * sum_w mus0[w][c] ----------------
__global__ void k_slc(const float* __restrict__ mus, float* __restrict__ S){
  int c = blockIdx.x*256 + threadIdx.x;
  float s = 0.f;
  for(int w=0;w<64;w++) s += mus[(size_t)w*DIM + c];
  S[c] = 5.0f * s;
}

// ---------------- K4d: emus_lab = S[c] + (e-1)*5*mus0 ----------------
__global__ void k_elab(const float* __restrict__ mus, const float* __restrict__ S,
                       float* __restrict__ emus_lab){
  int idx = blockIdx.x*256 + threadIdx.x;
  int c = idx % DIM;
  emus_lab[idx] = S[c] + (expf(1.0f)-1.0f)*5.0f*mus[idx];
}

// ---------------- K5: initial epoch prep (e=0): munorm, masksum, stamps, mus->bf16 hi/lo ----------------
__global__ void k_epoch_prep(const float* __restrict__ mus, float* munorm, float* masksum,
                             int* stamps, ushort* __restrict__ mbh, ushort* __restrict__ mbl){
  int w = blockIdx.x;
  float ss = 0.f;
#pragma unroll
  for(int q=0;q<6;q++){
    int c = threadIdx.x + 256*q;
    float v = mus[(size_t)w*DIM + c];
    ss += v*v;
    ushort h = f2bf(v);
    mbh[(size_t)w*DIM + c] = h;
    mbl[(size_t)w*DIM + c] = f2bf(v - bf2f(h));
  }
  __shared__ float red[4];
  float wsu = wave_sum(ss);
  if((threadIdx.x&63)==0) red[threadIdx.x>>6]=wsu;
  __syncthreads();
  if(threadIdx.x==0){
    munorm[w] = red[0]+red[1]+red[2]+red[3];
    masksum[w] = 315.0f + 5.0f*expf(1.0f);
    if(w < SB_NB) stamps[w] = 0;
  }
}

// ---------------- K6: dist via MFMA, in-block split-K=3 (3 waves) -> Kbf bf16 ----------------
// grid 780 x 192: each wave handles one 512-wide K chunk of the same 16 samples x 64 ways
__global__ __launch_bounds__(192,1) void k_dist(const ushort* __restrict__ mbh, const ushort* __restrict__ mbl,
                                                const ushort* __restrict__ Zhi, const float* __restrict__ munorm,
                                                ushort* __restrict__ Kbf){
  __shared__ float accsh[3][64][17];
  __shared__ float mnsh[64];
  int t = threadIdx.x;
  int lane = t & 63, kc = t >> 6;
  int l15 = lane & 15, quad = lane >> 4;
  int b = blockIdx.x;
  if(t < 64) mnsh[t] = munorm[t];
  int kbase = kc*512;
  const ushort* ap = Zhi + (size_t)(NL + b*16 + l15)*DIM + kbase + quad*8;
  const ushort* bhp[4]; const ushort* blp[4];
#pragma unroll
  for(int q=0;q<4;q++){
    bhp[q] = mbh + (size_t)(16*q + l15)*DIM + kbase + quad*8;
    blp[q] = mbl + (size_t)(16*q + l15)*DIM + kbase + quad*8;
  }
  f32x4 acc[4];
#pragma unroll
  for(int q=0;q<4;q++) acc[q] = (f32x4){0.f,0.f,0.f,0.f};
  short8 abuf[3], hbuf[3][4], lbuf[3][4];
#pragma unroll
  for(int s=0;s<2;s++){
    abuf[s] = *(const short8*)(ap + s*32);
#pragma unroll
    for(int q=0;q<4;q++){
      hbuf[s][q] = *(const short8*)(bhp[q] + s*32);
      lbuf[s][q] = *(const short8*)(blp[q] + s*32);
    }
  }
#pragma unroll
  for(int kt=0; kt<16; kt++){
    int cur = kt%3, nx = (kt+2)%3;
    if(kt+2 < 16){
      abuf[nx] = *(const short8*)(ap + (kt+2)*32);
#pragma unroll
      for(int q=0;q<4;q++){
        hbuf[nx][q] = *(const short8*)(bhp[q] + (kt+2)*32);
        lbuf[nx][q] = *(const short8*)(blp[q] + (kt+2)*32);
      }
    }
#pragma unroll
    for(int q=0;q<4;q++){
      acc[q] = __builtin_amdgcn_mfma_f32_16x16x32_bf16(abuf[cur], hbuf[cur][q], acc[q], 0,0,0);
      acc[q] = __builtin_amdgcn_mfma_f32_16x16x32_bf16(abuf[cur], lbuf[cur][q], acc[q], 0,0,0);
    }
  }
#pragma unroll
  for(int q=0;q<4;q++)
#pragma unroll
    for(int rg=0;rg<4;rg++)
      accsh[kc][lane][q*4+rg] = acc[q][rg];
  __syncthreads();
  // tail: reduce 3 chunks, exp, bf16 store (coalesced across w)
  for(int i = t; i < 1024; i += 192){
    int samp = i >> 6, w = i & 63;
    int ln = (samp>>2)*16 + (w&15);
    int idx = (w>>4)*4 + (samp&3);
    float s = accsh[0][ln][idx] + accsh[1][ln][idx] + accsh[2][ln][idx];
    float d2 = 1.0f + mnsh[w] - 2.0f*s;
    Kbf[(size_t)(b*16 + samp)*NW + w] = f2bf(expf(-10.0f * sqrtf(fmaxf(d2, 0.0f))));
  }
}

// ---------------- K7: persistent Sinkhorn (Kbf bf16 in, MThi bf16 out, fp64 residual) ----------------
__global__ __launch_bounds__(256,1) void k_sinkhorn(const ushort* __restrict__ Kbf,
                                                    ushort* __restrict__ MThi,
                                                    float* __restrict__ partials, int* __restrict__ stamps,
                                                    float* __restrict__ vprev, float* __restrict__ masksum){
  __shared__ __align__(16) float vsh[64];
  __shared__ float tmat[256][33];
  __shared__ float tq[8][64];
  __shared__ float tcol[64];
  __shared__ float mred[4];
  __shared__ float ctrl[1];
  int t = threadIdx.x, b = blockIdx.x;
  int iu = b*256 + t;
  bool active = iu < NU;
  float kr[64];
  if(active){
    const ushort* kp = Kbf + (size_t)iu*NW;
#pragma unroll
    for(int q=0;q<8;q++){
      short8 hh = *(const short8*)(kp + 8*q);
#pragma unroll
      for(int i=0;i<8;i++) kr[8*q+i] = bf2f((ushort)hh[i]);
    }
  } else {
#pragma unroll
    for(int j=0;j<64;j++) kr[j]=0.f;
  }
  if(t < 64) vsh[t] = vprev[t];
  float u = 1.0f, r_old = 0.0f;
  __syncthreads();
  int n = 0;
  while(true){
    // fp64 row dot: keeps the convergence residual off the fp32 noise floor (eps=1e-6)
    double s = 0.0;
#pragma unroll
    for(int q=0;q<16;q++){
      float4 vv = *(const float4*)&vsh[4*q];
      s += (double)kr[4*q]*vv.x + (double)kr[4*q+1]*vv.y + (double)kr[4*q+2]*vv.z + (double)kr[4*q+3]*vv.w;
    }
    float sf = (float)s;
    float r = u * sf;
    float diff = fabsf(r - r_old);
    float u_new = (active && sf > 0.f) ? 1.0f/sf : 0.0f;
    {
      float wmx = diff;
#pragma unroll
      for(int o=32;o;o>>=1) wmx = fmaxf(wmx, __shfl_xor(wmx,o));
      if((t&63)==0) mred[t>>6] = wmx;
    }
#pragma unroll
    for(int h=0;h<2;h++){
#pragma unroll
      for(int jj=0;jj<32;jj++) tmat[t][jj] = kr[32*h+jj]*u_new;
      __syncthreads();
      {
        int j = t & 31, q = t >> 5;
        float ps = 0.f;
#pragma unroll
        for(int rr=0;rr<32;rr++) ps += tmat[q*32+rr][j];
        tq[q][j] = ps;
      }
      __syncthreads();
      if(t < 32) tcol[32*h + t] = tq[0][t]+tq[1][t]+tq[2][t]+tq[3][t]+tq[4][t]+tq[5][t]+tq[6][t]+tq[7][t];
      __syncthreads();
    }
    int buf = n & 1;
    float* P = partials + buf*(SB_NB*66) + b*66;
    if(t < 64){
      __hip_atomic_store(&P[t], tcol[t], __ATOMIC_RELAXED, __HIP_MEMORY_SCOPE_AGENT);
    } else if(t == 64){
      float bm = fmaxf(fmaxf(mred[0],mred[1]), fmaxf(mred[2],mred[3]));
      __hip_atomic_store(&P[64], bm, __ATOMIC_RELAXED, __HIP_MEMORY_SCOPE_AGENT);
    }
    __syncthreads();
    if(t == 0){
      __threadfence();
      __hip_atomic_store(&stamps[b], n+1, __ATOMIC_RELEASE, __HIP_MEMORY_SCOPE_AGENT);
    }
    if(t < SB_NB){
      while(__hip_atomic_load(&stamps[t], __ATOMIC_ACQUIRE, __HIP_MEMORY_SCOPE_AGENT) <= n){}
    }
    __syncthreads();
    {
      int j = t & 63, q4 = t >> 6;
      float ps = 0.f, pm = 0.f;
      const float* PB = partials + buf*(SB_NB*66);
      for(int bb=q4; bb<SB_NB; bb+=4){
        ps += __hip_atomic_load(&PB[bb*66 + j], __ATOMIC_RELAXED, __HIP_MEMORY_SCOPE_AGENT);
        if(j==0) pm = fmaxf(pm, __hip_atomic_load(&PB[bb*66 + 64], __ATOMIC_RELAXED, __HIP_MEMORY_SCOPE_AGENT));
      }
      tq[q4][j] = ps;
      if(j==0) mred[q4] = pm;
    }
    __syncthreads();
    if(t==0) ctrl[0] = fmaxf(fmaxf(mred[0],mred[1]), fmaxf(mred[2],mred[3]));
    __syncthreads();
    float M = ctrl[0];
    if(M <= EPSC || n >= MAXIT) break;
    u = u_new; r_old = r; n++;
    if(t < 64) vsh[t] = (float)NQ / (tq[0][t]+tq[1][t]+tq[2][t]+tq[3][t]);
    __syncthreads();
  }
  // final plan colsums -> masksum
#pragma unroll
  for(int h=0;h<2;h++){
#pragma unroll
    for(int jj=0;jj<32;jj++) tmat[t][jj] = kr[32*h+jj]*u;
    __syncthreads();
    {
      int j = t & 31, q = t >> 5;
      float ps = 0.f;
#pragma unroll
      for(int rr=0;rr<32;rr++) ps += tmat[q*32+rr][j];
      tq[q][j] = ps;
    }
    __syncthreads();
    if(t < 32) tcol[32*h + t] = tq[0][t]+tq[1][t]+tq[2][t]+tq[3][t]+tq[4][t]+tq[5][t]+tq[6][t]+tq[7][t];
    __syncthreads();
  }
  if(t < 64) atomicAdd(&masksum[t], tcol[t]*vsh[t]);
  // store plan transposed, bf16 hi only (pitch NUP; 49*256 == NUP exactly)
  if(active){
#pragma unroll
    for(int j=0;j<64;j++)
      MThi[(size_t)j*NUP + iu] = f2bf(kr[j]*u*vsh[j]);
  } else {
#pragma unroll
    for(int j=0;j<64;j++)
      MThi[(size_t)j*NUP + iu] = 0;
  }
  if(b==0 && t<64) vprev[t] = vsh[t];
}

// ---------------- K8: emus via MFMA, depth-2 prefetch ----------------
__global__ __launch_bounds__(64) void k_emus(const ushort* __restrict__ MThi, const ushort* __restrict__ ZThi,
                                             float* __restrict__ part){
  int t = threadIdx.x, l15 = t&15, quad = t>>4;
  int cx = blockIdx.x, iy = blockIdx.y;
  int start = iy*1568;
  const ushort* ap[4];
#pragma unroll
  for(int q=0;q<4;q++) ap[q] = MThi + (size_t)(16*q + l15)*NUP + start + quad*8;
  const ushort* bp = ZThi + (size_t)(cx*16 + l15)*NUP + start + quad*8;
  f32x4 acc[4];
#pragma unroll
  for(int q=0;q<4;q++) acc[q] = (f32x4){0.f,0.f,0.f,0.f};
  short8 ab[3][4], bb[3];
#pragma unroll
  for(int s=0;s<2;s++){
#pragma unroll
    for(int q=0;q<4;q++) ab[s][q] = *(const short8*)(ap[q] + s*32);
    bb[s] = *(const short8*)(bp + s*32);
  }
#pragma unroll
  for(int kt=0; kt<49; kt++){
    int cur = kt%3, nx = (kt+2)%3;
    if(kt+2 < 49){
#pragma unroll
      for(int q=0;q<4;q++) ab[nx][q] = *(const short8*)(ap[q] + (kt+2)*32);
      bb[nx] = *(const short8*)(bp + (kt+2)*32);
    }
#pragma unroll
    for(int q=0;q<4;q++)
      acc[q] = __builtin_amdgcn_mfma_f32_16x16x32_bf16(ab[cur][q], bb[cur], acc[q], 0,0,0);
  }
  float* dst = part + (size_t)iy*(NW*DIM);
#pragma unroll
  for(int q=0;q<4;q++)
#pragma unroll
    for(int rg=0;rg<4;rg++)
      dst[(size_t)(16*q + quad*4 + rg)*DIM + cx*16 + l15] = acc[q][rg];
}

// ---------------- K9: fused mus update + next-epoch prep ----------------
__global__ void k_mus_step(float* __restrict__ mus, const float* __restrict__ emus_lab,
                           const float* __restrict__ part, float* munorm, float* masksum,
                           int* stamps, ushort* __restrict__ mbh, ushort* __restrict__ mbl){
  int w = blockIdx.x;
  float msum = masksum[w];
  float ss = 0.f;
#pragma unroll
  for(int q=0;q<6;q++){
    int c = threadIdx.x + 256*q;
    size_t idx = (size_t)w*DIM + c;
    float e = emus_lab[idx];
#pragma unroll
    for(int s=0;s<8;s++) e += part[(size_t)s*(NW*DIM) + idx];
    float nm = mus[idx] + ALPHA*(e/msum - mus[idx]);
    mus[idx] = nm;
    ss += nm*nm;
    ushort h = f2bf(nm);
    mbh[idx] = h;
    mbl[idx] = f2bf(nm - bf2f(h));
  }
  __shared__ float red[4];
  float wsu = wave_sum(ss);
  if((threadIdx.x&63)==0) red[threadIdx.x>>6]=wsu;
  __syncthreads();
  if(threadIdx.x==0){
    munorm[w] = red[0]+red[1]+red[2]+red[3];
    masksum[w] = 315.0f + 5.0f*expf(1.0f);
    if(w < SB_NB) stamps[w] = 0;
  }
}

// ---------------- K10a: labeled onehot rows ----------------
__global__ void k_out_lab(const int* __restrict__ labels, float* __restrict__ out){
  int idx = blockIdx.x*256 + threadIdx.x;
  if(idx < NL*NW){
    int i = idx >> 6, w = idx & 63;
    out[idx] = (labels[i]==w) ? 1.0f : 0.0f;
  }
}

// ---------------- K10b: unlabeled rows: out = log(plan) ----------------
__global__ __launch_bounds__(256) void k_out_u(const ushort* __restrict__ MThi, float* __restrict__ out){
  __shared__ float P[64][68];
  int b = blockIdx.x;
  int iu0 = b*64;
  int t = threadIdx.x;
  int w = t>>2, ch = (t&3)*16;
  const ushort* ph = MThi + (size_t)w*NUP + iu0 + ch;
  short8 h0 = *(const short8*)ph, h1 = *(const short8*)(ph+8);
#pragma unroll
  for(int k=0;k<8;k++){
    P[ch+k][w]   = logf(bf2f((ushort)h0[k]));
    P[ch+8+k][w] = logf(bf2f((ushort)h1[k]));
  }
  __syncthreads();
  int r = t>>2, c0 = (t&3)*16;
  float4* dst = (float4*)(out + (size_t)(NL + iu0 + r)*NW + c0);
#pragma unroll
  for(int g=0;g<4;g++) dst[g] = *(float4*)&P[r][c0+4*g];
}

// ---------------- K11: accuracy ----------------
__global__ void k_acc(const ushort* __restrict__ MThi, const int* __restrict__ labels, float* matchcount){
  int iu = blockIdx.x*256 + threadIdx.x;
  float m = 0.f;
  if(iu < NU){
    float best = -1.f; int bj = 0;
#pragma unroll 8
    for(int w=0;w<64;w++){
      float v = bf2f(MThi[(size_t)w*NUP + iu]);
      if(v > best){ best = v; bj = w; }
    }
    m = (labels[NL+iu] == bj) ? 1.f : 0.f;
  }
  float ws = wave_sum(m);
  __shared__ float red[4];
  if((threadIdx.x&63)==0) red[threadIdx.x>>6]=ws;
  __syncthreads();
  if(threadIdx.x==0) atomicAdd(matchcount, red[0]+red[1]+red[2]+red[3]);
}

// ---------------- K12 ----------------
__global__ void k_fin(const float* matchcount, float* __restrict__ out){
  out[(size_t)NTOT*NW]     = (*matchcount) * (1.0f/(float)NU);
  out[(size_t)NTOT*NW + 1] = 0.0f;
}

// ---------------- launch ----------------
extern "C" void kernel_launch(void* const* d_in, const int* in_sizes, int n_in,
                              void* d_out, int out_size, void* d_ws, size_t ws_size,
                              hipStream_t stream){
  const float* X = (const float*)d_in[0];
  const int* labels = (const int*)d_in[1];
  float* out = (float*)d_out;
  float* ws = (float*)d_ws;

  // ws layout (float offsets), total 20,757,576 fl = 83.0 MB (< proven-safe 85.94 MB)
  float*  matchcount = ws + 0;
  float*  munorm     = ws + 4;
  float*  masksum    = ws + 68;
  float*  vprev      = ws + 132;
  float*  csum_l     = ws + 196;
  float*  csum_u     = ws + 1732;
  int*    stamps     = (int*)(ws + 3268);        // 49 ints (region to 3332)
  float*  partials   = ws + 3332;                // 2*49*66 = 6468 -> 9800
  float*  Slc        = ws + 9800;                // 1536 -> 11336
  float*  mus        = ws + 11336;               // 98304 -> 109640
  float*  emus_lab   = ws + 109640;              // 98304 -> 207944
  ushort* mbh        = (ushort*)(ws + 207944);   // 49152 fl -> 257096
  ushort* mbl        = (ushort*)(ws + 257096);   // -> 306248
  // union region U (786,432 fl -> 1,092,680): lifetimes disjoint within an epoch:
  //   Kbf  (798,720 us = 399,360 fl)  live [k_dist -> k_sinkhorn load]
  //   part (8*98,304 = 786,432 fl)    live [k_emus -> k_mus_step]
  float*  U          = ws + 306248;
  ushort* Kbf        = (ushort*)U;
  float*  part       = U;
  ushort* MThi       = (ushort*)(ws + 1092680);  // 401,408 us = 200,704 fl -> 1,293,384
  ushort* Zhi        = (ushort*)(ws + 1293384);  // 9,830,400 fl -> 11,123,784
  ushort* ZThi       = (ushort*)(ws + 11123784); // 9,633,792 fl -> 20,757,576
  if(ws_size < (size_t)20757576*4) return;

  hipMemsetAsync(ws, 0, 3332*sizeof(float), stream);

  k_prep<<<3200,256,0,stream>>>(X, Zhi);
  k_colsum<<<dim3(3,100),256,0,stream>>>(Zhi, csum_l, csum_u);
  k_finalize_means<<<12,256,0,stream>>>(csum_l, csum_u);
  k_center<<<3200,256,0,stream>>>(Zhi, csum_l, csum_u);
  k_ztrans<<<dim3(195,24),256,0,stream>>>(Zhi, ZThi);
  k_ztpad<<<384,256,0,stream>>>(ZThi);
  k_mus_init<<<64,256,0,stream>>>(Zhi, mus);
  k_vinit<<<1,64,0,stream>>>(vprev);
  k_slc<<<6,256,0,stream>>>(mus, Slc);
  k_elab<<<384,256,0,stream>>>(mus, Slc, emus_lab);
  k_epoch_prep<<<64,256,0,stream>>>(mus, munorm, masksum, stamps, mbh, mbl);

  for(int e=0; e<=EPOCHS; e++){
    k_dist<<<780,192,0,stream>>>(mbh, mbl, Zhi, munorm, Kbf);
    k_sinkhorn<<<SB_NB,256,0,stream>>>(Kbf, MThi, partials, stamps, vprev, masksum);
    if(e < EPOCHS){
      k_emus<<<dim3(96,8),64,0,stream>>>(MThi, ZThi, part);
      k_mus_step<<<64,256,0,stream>>>(mus, emus_lab, part, munorm, masksum, stamps, mbh, mbl);
    }
  }
  k_out_lab<<<80,256,0,stream>>>(labels, out);
  k_out_u<<<195,256,0,stream>>>(MThi, out);
  k_acc<<<49,256,0,stream>>>(MThi, labels, matchcount);
  k_fin<<<1,1,0,stream>>>(matchcount, out);
}